// Round 9
// baseline (570.606 us; speedup 1.0000x reference)
//
#include <hip/hip_runtime.h>
#include <cstdint>
#include <cstddef>

#define NB 4
#define HH 96
#define WW 96
#define CHN 256
#define CC 64
#define LL 9216
#define NHASH 4
#define HBK 64
#define CHK 144
#define NCHUNK 64
#define NJ 36864   // NHASH * LL

typedef __attribute__((ext_vector_type(8))) short bf16x8;
typedef __attribute__((ext_vector_type(8))) unsigned short u16x8;
typedef __attribute__((ext_vector_type(4))) float f32x4;

__device__ __forceinline__ unsigned short f2b(float f) {
    unsigned int x = __float_as_uint(f);
    x += 0x7FFFu + ((x >> 16) & 1u);
    return (unsigned short)(x >> 16);
}
__device__ __forceinline__ float b2f(unsigned short u) {
    return __uint_as_float(((unsigned int)u) << 16);
}

// ---------------------------------------------------------------- input fp32 -> bf16 hi + bf16 lo residual
__global__ __launch_bounds__(256) void cvt_in_hilo_k(const float* __restrict__ in,
                                                     unsigned short* __restrict__ hi,
                                                     unsigned short* __restrict__ lo)
{
    size_t g = ((size_t)blockIdx.x * 256 + threadIdx.x) * 8;
    float4 v0 = *(const float4*)(in + g);
    float4 v1 = *(const float4*)(in + g + 4);
    float xs[8] = {v0.x, v0.y, v0.z, v0.w, v1.x, v1.y, v1.z, v1.w};
    u16x8 h, l;
#pragma unroll
    for (int i = 0; i < 8; i++) {
        unsigned short hv = f2b(xs[i]);
        h[i] = hv;
        l[i] = f2b(xs[i] - b2f(hv));
    }
    *(u16x8*)(hi + g) = h;
    *(u16x8*)(lo + g) = l;
}

// ---------------------------------------------------------------- w_match [tap][ci][64] fp32 -> wmT [tap][co=64][ci=256] bf16 hi/lo
__global__ __launch_bounds__(256) void cvt_wm_hilo_k(const float* __restrict__ w,
                                                     unsigned short* __restrict__ hiT,
                                                     unsigned short* __restrict__ loT)
{
    __shared__ float tl[32][33];
    const int tap = blockIdx.z;
    const int c0 = blockIdx.x * 32;   // ci
    const int o0 = blockIdx.y * 32;   // co
    const int tx = threadIdx.x & 31, ty0 = threadIdx.x >> 5;
#pragma unroll
    for (int i = 0; i < 32; i += 8)
        tl[ty0 + i][tx] = w[((size_t)tap * 256 + c0 + ty0 + i) * 64 + o0 + tx];
    __syncthreads();
#pragma unroll
    for (int i = 0; i < 32; i += 8) {
        float v = tl[tx][ty0 + i];
        unsigned short h = f2b(v);
        size_t o = ((size_t)tap * 64 + o0 + ty0 + i) * 256 + c0 + tx;
        hiT[o] = h;
        loT[o] = f2b(v - b2f(h));
    }
}

// ---------------------------------------------------------------- MFMA conv 3x3 (match path, split-bf16 ~fp32 precision)
#define ASTR 40
__global__ __launch_bounds__(256, 2) void conv_match_mfma_k(
    const unsigned short* __restrict__ in_hi, const unsigned short* __restrict__ in_lo,
    const unsigned short* __restrict__ wmT_hi, const unsigned short* __restrict__ wmT_lo,
    const float* __restrict__ bias, float* __restrict__ xm)
{
    __shared__ short Ah[64 * ASTR], Al[64 * ASTR];
    __shared__ short Bh[64 * ASTR], Bl[64 * ASTR];
    const int n = blockIdx.z, p0 = blockIdx.x * 64;
    const int tid = threadIdx.x;
    const int w = tid >> 6;
    const int lane = tid & 63, lm = lane & 15, lq = lane >> 4;
    const int r = tid >> 2, q8 = (tid & 3) * 8;      // staging: row 0..63, 8-short quarter
    const int p = p0 + r, py = p / WW, px = p % WW;
    const unsigned short* hiN = in_hi + (size_t)n * LL * CHN;
    const unsigned short* loN = in_lo + (size_t)n * LL * CHN;

    f32x4 acc[4];
#pragma unroll
    for (int b = 0; b < 4; b++) acc[b] = (f32x4){0.f, 0.f, 0.f, 0.f};

    for (int tap = 0; tap < 9; tap++) {
        const int ky = tap / 3, kx = tap - ky * 3;
        const int sy = py + ky - 1, sx = px + kx - 1;
        const bool valid = ((unsigned)sy < HH) && ((unsigned)sx < WW);
        const unsigned short* ah = hiN + (size_t)(sy * WW + sx) * CHN + q8;
        const unsigned short* al = loN + (size_t)(sy * WW + sx) * CHN + q8;
        const unsigned short* bh = wmT_hi + ((size_t)tap * 64 + r) * 256 + q8;
        const unsigned short* bl = wmT_lo + ((size_t)tap * 64 + r) * 256 + q8;
        for (int ci0 = 0; ci0 < 256; ci0 += 32) {
            u16x8 avh = (u16x8){0,0,0,0,0,0,0,0}, avl = (u16x8){0,0,0,0,0,0,0,0};
            if (valid) {
                avh = *(const u16x8*)(ah + ci0);
                avl = *(const u16x8*)(al + ci0);
            }
            u16x8 bvh = *(const u16x8*)(bh + ci0);
            u16x8 bvl = *(const u16x8*)(bl + ci0);
            __syncthreads();
            *(u16x8*)&Ah[r * ASTR + q8] = avh;
            *(u16x8*)&Al[r * ASTR + q8] = avl;
            *(u16x8*)&Bh[r * ASTR + q8] = bvh;
            *(u16x8*)&Bl[r * ASTR + q8] = bvl;
            __syncthreads();
            bf16x8 afh = *(const bf16x8*)&Ah[(w * 16 + lm) * ASTR + lq * 8];
            bf16x8 afl = *(const bf16x8*)&Al[(w * 16 + lm) * ASTR + lq * 8];
#pragma unroll
            for (int nt = 0; nt < 4; nt++) {
                bf16x8 bfh = *(const bf16x8*)&Bh[(nt * 16 + lm) * ASTR + lq * 8];
                bf16x8 bfl = *(const bf16x8*)&Bl[(nt * 16 + lm) * ASTR + lq * 8];
                acc[nt] = __builtin_amdgcn_mfma_f32_16x16x32_bf16(afh, bfh, acc[nt], 0, 0, 0);
                acc[nt] = __builtin_amdgcn_mfma_f32_16x16x32_bf16(afh, bfl, acc[nt], 0, 0, 0);
                acc[nt] = __builtin_amdgcn_mfma_f32_16x16x32_bf16(afl, bfh, acc[nt], 0, 0, 0);
            }
        }
    }
    float bvv[4];
#pragma unroll
    for (int nt = 0; nt < 4; nt++) bvv[nt] = bias[nt * 16 + lm];
    float* outN = xm + (size_t)n * LL * 64;
#pragma unroll
    for (int r4 = 0; r4 < 4; r4++) {
        int row = p0 + w * 16 + lq * 4 + r4;
        float* od = outN + (size_t)row * 64;
#pragma unroll
        for (int nt = 0; nt < 4; nt++)
            od[nt * 16 + lm] = acc[nt][r4] + bvv[nt];
    }
}

// ---------------------------------------------------------------- fp32 transpose (match embedding) + bf16 copy
__global__ __launch_bounds__(256) void transpose_k(const float* __restrict__ in, float* __restrict__ out,
                                                   unsigned short* __restrict__ out_bf, int R, int Cc)
{
    __shared__ float tl[32][33];
    const int n = blockIdx.z;
    const size_t base = (size_t)n * R * Cc;
    int c0 = blockIdx.x * 32, r0 = blockIdx.y * 32;
    int tx = threadIdx.x & 31, ty0 = threadIdx.x >> 5;
#pragma unroll
    for (int i = 0; i < 32; i += 8)
        tl[ty0 + i][tx] = in[base + (size_t)(r0 + ty0 + i) * Cc + c0 + tx];
    __syncthreads();
#pragma unroll
    for (int i = 0; i < 32; i += 8) {
        float v = tl[tx][ty0 + i];
        size_t o = base + (size_t)(c0 + ty0 + i) * R + r0 + tx;
        out[o] = v;
        out_bf[o] = f2b(v);
    }
}

// ---------------------------------------------------------------- w_asm [tap][ci][co] fp32 -> wT [tap][co][ci] bf16
__global__ __launch_bounds__(256) void cvt_wT_k(const float* __restrict__ w, unsigned short* __restrict__ wT)
{
    __shared__ float tl[32][33];
    const int tap = blockIdx.z;
    const int c0 = blockIdx.x * 32;
    const int o0 = blockIdx.y * 32;
    const int tx = threadIdx.x & 31, ty0 = threadIdx.x >> 5;
#pragma unroll
    for (int i = 0; i < 32; i += 8)
        tl[ty0 + i][tx] = w[((size_t)tap * 256 + c0 + ty0 + i) * 256 + o0 + tx];
    __syncthreads();
#pragma unroll
    for (int i = 0; i < 32; i += 8)
        wT[((size_t)tap * 256 + o0 + ty0 + i) * 256 + c0 + tx] = f2b(tl[tx][ty0 + i]);
}

// ---------------------------------------------------------------- MFMA conv 3x3 (value path, bf16)
__global__ __launch_bounds__(256) void conv_mfma_k(
    const unsigned short* __restrict__ in_bf, const unsigned short* __restrict__ wT,
    const float* __restrict__ bias, unsigned short* __restrict__ ya_bf)
{
    __shared__ short As[128 * 32];
    __shared__ short Bs[128 * 32];
    const int n = blockIdx.z, p0 = blockIdx.x * 128, co0 = blockIdx.y * 128;
    const int tid = threadIdx.x;
    const int w = tid >> 6, wr = w >> 1, wc = w & 1;
    const int lane = tid & 63, lm = lane & 15, lq = lane >> 4;
    const int r = tid >> 1, hf = tid & 1;
    const int p = p0 + r, py = p / WW, px = p % WW;
    const unsigned short* inN = in_bf + (size_t)n * LL * CHN;

    f32x4 acc[4][4];
#pragma unroll
    for (int a = 0; a < 4; a++)
#pragma unroll
        for (int b = 0; b < 4; b++) acc[a][b] = (f32x4){0.f, 0.f, 0.f, 0.f};

    for (int tap = 0; tap < 9; tap++) {
        const int ky = tap / 3, kx = tap - ky * 3;
        const int sy = py + ky - 1, sx = px + kx - 1;
        const bool valid = ((unsigned)sy < HH) && ((unsigned)sx < WW);
        const unsigned short* asrc = inN + (size_t)(sy * WW + sx) * CHN + hf * 16;
        const unsigned short* bsrc = wT + ((size_t)tap * 256 + co0 + r) * 256 + hf * 16;
        for (int ci0 = 0; ci0 < 256; ci0 += 32) {
            u16x8 av0 = (u16x8){0,0,0,0,0,0,0,0}, av1 = (u16x8){0,0,0,0,0,0,0,0};
            if (valid) {
                av0 = *(const u16x8*)(asrc + ci0);
                av1 = *(const u16x8*)(asrc + ci0 + 8);
            }
            u16x8 bv0 = *(const u16x8*)(bsrc + ci0);
            u16x8 bv1 = *(const u16x8*)(bsrc + ci0 + 8);
            __syncthreads();
            *(u16x8*)&As[r * 32 + hf * 16]     = av0;
            *(u16x8*)&As[r * 32 + hf * 16 + 8] = av1;
            *(u16x8*)&Bs[r * 32 + hf * 16]     = bv0;
            *(u16x8*)&Bs[r * 32 + hf * 16 + 8] = bv1;
            __syncthreads();
            bf16x8 af[4], bf[4];
#pragma unroll
            for (int mt = 0; mt < 4; mt++)
                af[mt] = *(const bf16x8*)&As[(wr * 64 + mt * 16 + lm) * 32 + lq * 8];
#pragma unroll
            for (int nt = 0; nt < 4; nt++)
                bf[nt] = *(const bf16x8*)&Bs[(wc * 64 + nt * 16 + lm) * 32 + lq * 8];
#pragma unroll
            for (int mt = 0; mt < 4; mt++)
#pragma unroll
                for (int nt = 0; nt < 4; nt++)
                    acc[mt][nt] = __builtin_amdgcn_mfma_f32_16x16x32_bf16(af[mt], bf[nt], acc[mt][nt], 0, 0, 0);
        }
    }
    float bv[4];
#pragma unroll
    for (int nt = 0; nt < 4; nt++) bv[nt] = bias[co0 + wc * 64 + nt * 16 + lm];
#pragma unroll
    for (int mt = 0; mt < 4; mt++) {
#pragma unroll
        for (int r4 = 0; r4 < 4; r4++) {
            int row = p0 + wr * 64 + mt * 16 + lq * 4 + r4;
            unsigned short* od = ya_bf + ((size_t)n * LL + row) * CHN + co0 + wc * 64;
#pragma unroll
            for (int nt = 0; nt < 4; nt++)
                od[nt * 16 + lm] = f2b(acc[mt][nt][r4] + bv[nt]);
        }
    }
}

// ---------------------------------------------------------------- bf16 transpose: ya_bf (viewed [256][9216]) -> yaT [9216][256]
__global__ __launch_bounds__(256) void transpose_bf_k(const unsigned short* __restrict__ in,
                                                      unsigned short* __restrict__ out)
{
    __shared__ unsigned short tl[64][65];
    const int n = blockIdx.z;
    const size_t base = (size_t)n * LL * CHN;
    const int t0 = blockIdx.x * 64, e0 = blockIdx.y * 64;
    const int tx = threadIdx.x & 63, ty0 = threadIdx.x >> 6;
#pragma unroll
    for (int i = 0; i < 16; i++) {
        int row = ty0 + i * 4;
        tl[row][tx] = in[base + (size_t)(e0 + row) * LL + t0 + tx];
    }
    __syncthreads();
#pragma unroll
    for (int i = 0; i < 16; i++) {
        int row = ty0 + i * 4;
        out[base + (size_t)(t0 + row) * CHN + e0 + tx] = tl[tx][row];
    }
}

// ---------------------------------------------------------------- hashing: codes + squared norms (fp32!)
__global__ __launch_bounds__(256) void hash_k(const float* __restrict__ xmT, const float* __restrict__ rot,
                                              int* __restrict__ codes, float* __restrict__ ssq)
{
    __shared__ float rs[32 * 68];   // [i][f], stride 68, this block's hash only
    const int h = blockIdx.y;
    for (int e = threadIdx.x; e < 2048; e += 256) {
        int hi = e >> 6, f = e & 63;
        rs[hi * 68 + f] = rot[f * 128 + h * 32 + hi];
    }
    __syncthreads();
    int g = blockIdx.x * 256 + threadIdx.x;
    int n = g / LL, t = g % LL;
    float4 x4[16];
    const float* src = xmT + (size_t)g * CC;
#pragma unroll
    for (int f4 = 0; f4 < 16; f4++) x4[f4] = *(const float4*)(src + f4 * 4);
    if (h == 0) {
        float ss = 0.f;
#pragma unroll
        for (int f4 = 0; f4 < 16; f4++)
            ss += x4[f4].x * x4[f4].x + x4[f4].y * x4[f4].y + x4[f4].z * x4[f4].z + x4[f4].w * x4[f4].w;
        ssq[g] = ss;
    }
    float bp = -1e30f, bn = -1e30f;
    int ip = 0, inn = 0;
    for (int i = 0; i < 32; i++) {
        const float* rr = &rs[i * 68];
        float d0 = 0.f, d1 = 0.f, d2 = 0.f, d3 = 0.f;
#pragma unroll
        for (int f4 = 0; f4 < 16; f4++) {
            float4 r4 = *(const float4*)(rr + f4 * 4);
            d0 = fmaf(x4[f4].x, r4.x, d0);
            d1 = fmaf(x4[f4].y, r4.y, d1);
            d2 = fmaf(x4[f4].z, r4.z, d2);
            d3 = fmaf(x4[f4].w, r4.w, d3);
        }
        float d = (d0 + d1) + (d2 + d3);
        if (d > bp) { bp = d; ip = i; }
        if (-d > bn) { bn = -d; inn = i; }
    }
    int code = (bp >= bn) ? ip : (32 + inn);
    codes[(size_t)n * NJ + h * LL + t] = code + h * HBK;
}

// ---------------------------------------------------------------- stable counting sort (256 buckets)
__global__ __launch_bounds__(256) void sort_hist_k(const int* __restrict__ codes, int* __restrict__ hist,
                                                   int* __restrict__ rank)
{
    __shared__ int lhw[4][256];
    const int n = blockIdx.y, seg = blockIdx.x, tid = threadIdx.x;
    const int w = tid >> 6, lane = tid & 63;
    int j = seg * 256 + tid;
    int c = codes[(size_t)n * NJ + j];
    for (int e = tid; e < 1024; e += 256) ((int*)lhw)[e] = 0;
    __syncthreads();
    unsigned long long eq = ~0ull;
#pragma unroll
    for (int b = 0; b < 8; b++) {
        unsigned long long m = __ballot((c >> b) & 1);
        eq &= ((c >> b) & 1) ? m : ~m;
    }
    int rw = __popcll(eq & ((1ull << lane) - 1ull));   // rank within wave (tid order)
    int cntw = __popcll(eq);                           // class count in this wave
    if (rw == 0) lhw[w][c] = cntw;                     // unique (w,c) writer
    __syncthreads();
    int base = 0;
    if (w > 0) base += lhw[0][c];
    if (w > 1) base += lhw[1][c];
    if (w > 2) base += lhw[2][c];
    rank[(size_t)n * NJ + j] = base + rw;
    hist[(size_t)n * NJ + tid * 144 + seg] = lhw[0][tid] + lhw[1][tid] + lhw[2][tid] + lhw[3][tid];
}

__global__ __launch_bounds__(256) void sort_scan_k(int* __restrict__ hist)
{
    const int n = blockIdx.x;
    const int key = threadIdx.x;
    int* hn = hist + (size_t)n * NJ;
    int sum = 0;
    for (int s = 0; s < 144; s++) sum += hn[key * 144 + s];
    __shared__ int sc[256];
    sc[key] = sum;
    __syncthreads();
    for (int off = 1; off < 256; off <<= 1) {
        int v = (key >= off) ? sc[key - off] : 0;
        __syncthreads();
        sc[key] += v;
        __syncthreads();
    }
    int run = sc[key] - sum;   // exclusive prefix
    for (int s = 0; s < 144; s++) { int v = hn[key * 144 + s]; hn[key * 144 + s] = run; run += v; }
}

__global__ __launch_bounds__(256) void sort_scatter_k(const int* __restrict__ codes, const int* __restrict__ rank,
                                                      const int* __restrict__ hist, int* __restrict__ sidx,
                                                      int* __restrict__ undo)
{
    const int n = blockIdx.y, seg = blockIdx.x, tid = threadIdx.x;
    int j = seg * 256 + tid;
    int c = codes[(size_t)n * NJ + j];
    int dest = hist[(size_t)n * NJ + c * 144 + seg] + rank[(size_t)n * NJ + j];
    sidx[(size_t)n * NJ + dest] = j;
    undo[(size_t)n * NJ + j] = dest;
}

// ---------------------------------------------------------------- MFMA attention v6: split-P for 2 blocks/CU
// v5 (124us, stable across 3 attempts) was latency/lockstep-bound at 1 block/CU
// (96.8KB LDS): 16 waves hit every barrier and V-gather bubble together; MfmaUtil
// 15.5%, VALUBusy 44%, HBM 16% — nothing saturated. v6 halves the P buffer by
// splitting each chunk's QK/PV into phase A (mt 0..4, 80 rows) and phase B
// (mt 5..8, 64 rows reusing the same buffer): LDS 96.8 -> 74KB -> 2 blocks/CU
// (32 waves), so the co-resident block's MFMA fills this block's stalls (m114
// overlap). Costs 4 barriers/chunk instead of 2 — paid for by the overlap.
// __launch_bounds__(1024, 8) pins the VGPR budget at 64 (current usage is exactly
// 64) so occupancy isn't regalloc-limited. lsum ownership stays wave w <-> row-
// tile w (waves 0-4 reduce in phase A, waves 5-8 in phase B); epilogue unchanged.
#define QSTR 72     // Q/K row stride in shorts
#define PSTR 164    // P row stride in shorts (conflict-free write quadrants)
#define PROWS 80    // P buffer rows (phase A: 80, phase B reuses rows 0..63)
__global__ __launch_bounds__(1024, 8) void attn_mfma_k(
    const unsigned short* __restrict__ xmT_bf, const unsigned short* __restrict__ yaT,
    const float* __restrict__ ssq, const int* __restrict__ sidx,
    unsigned short* __restrict__ Osort, float* __restrict__ bs)
{
    __shared__ short Qs[144 * QSTR];
    __shared__ short Ks[144 * QSTR];
    __shared__ short Ps[PROWS * PSTR];
    __shared__ int   tIdx[432];
    __shared__ int   voff[432];
    __shared__ float nfs[432];
    __shared__ float qlen[432];
    __shared__ float lsum[144];
    __shared__ float linv[144];

    const int k = blockIdx.x, h = blockIdx.y, n = blockIdx.z;
    const int tid = threadIdx.x;
    const int w = tid >> 6, lane = tid & 63;
    const int lm = lane & 15, lq = lane >> 4;
    const size_t sbase = (size_t)n * NJ + (size_t)h * LL;

    if (tid < 432) {
        int cc = tid / CHK, rr = tid - cc * CHK;
        int c = (cc == 0) ? k : (cc == 1 ? (k + NCHUNK - 1) & (NCHUNK - 1) : (k + 1) & (NCHUNK - 1));
        int j = sidx[sbase + c * CHK + rr];
        int t = j % LL;
        tIdx[tid] = t;
        voff[tid] = t * (CHN * 2);
        float m = fmaxf(ssq[(size_t)n * LL + t], 5e-5f);
        float nf = rsqrtf(m);
        nfs[tid] = nf;
        qlen[tid] = m * nf;   // sqrt(m) = |q| clamped
    }
    __syncthreads();   // tIdx/voff/nfs/qlen ready

    // stage Q rows (raw bf16)
    const int sr = tid >> 3, sj = (tid & 7) * 8;
    const int sr2 = (tid + 1024) >> 3, sj2 = (tid & 7) * 8;
    {
        u16x8 v = *(const u16x8*)(xmT_bf + ((size_t)n * LL + tIdx[sr]) * CC + sj);
        *(u16x8*)&Qs[sr * QSTR + sj] = v;
        if (tid < 128) {
            u16x8 v2 = *(const u16x8*)(xmT_bf + ((size_t)n * LL + tIdx[sr2]) * CC + sj2);
            *(u16x8*)&Qs[sr2 * QSTR + sj2] = v2;
        }
    }
    // zero P pad columns 144..159 for all 80 buffer rows once (QK writes touch
    // cols 0..143 only, both phases -> pads stay 0, NaN-safe for lsum/PV)
    for (int e = tid; e < 1280; e += 1024) {
        int r = e >> 4, c = 144 + (e & 15);
        Ps[r * PSTR + c] = 0;
    }
    // T14: issue chunk-1 K loads into registers now (consumed at top of chunk 1)
    u16x8 kreg0, kreg1;
    kreg0 = *(const u16x8*)(xmT_bf + ((size_t)n * LL + tIdx[CHK + sr]) * CC + sj);
    if (tid < 128)
        kreg1 = *(const u16x8*)(xmT_bf + ((size_t)n * LL + tIdx[CHK + sr2]) * CC + sj2);

    const char* vbase = (const char*)(yaT + (size_t)n * LL * CHN + w * 16 + lm);
    f32x4 accO[9];
#pragma unroll
    for (int mt = 0; mt < 9; mt++) accO[mt] = (f32x4){0.f, 0.f, 0.f, 0.f};
    f32x4 accL = (f32x4){0.f, 0.f, 0.f, 0.f};
    bf16x8 onesF, onesL;
#pragma unroll
    for (int i = 0; i < 8; i++) {
        onesF[i] = (short)0x3F80;
        onesL[i] = (lq < 2) ? (short)0x3F80 : (short)0;   // mask pad keys 144..159 (k-step 4, lq>=2)
    }

    for (int cc = 0; cc < 3; cc++) {
        const int c144 = cc * CHK;
        if (cc > 0) {
            // write prefetched K(cc) regs -> LDS. Safe: all QK-B(cc-1) reads of Ks
            // completed before the previous chunk's B4 barrier.
            *(u16x8*)&Ks[sr * QSTR + sj] = kreg0;
            if (tid < 128) *(u16x8*)&Ks[sr2 * QSTR + sj2] = kreg1;
        }
        if (cc < 2) {
            kreg0 = *(const u16x8*)(xmT_bf + ((size_t)n * LL + tIdx[(cc + 1) * CHK + sr]) * CC + sj);
            if (tid < 128)
                kreg1 = *(const u16x8*)(xmT_bf + ((size_t)n * LL + tIdx[(cc + 1) * CHK + sr2]) * CC + sj2);
        }
        // V B-frag gathers from global — issued early, consumed in PV-A/PV-B
        bf16x8 vfrag[5];
#pragma unroll
        for (int ks = 0; ks < 5; ks++) {
            int kb = ks * 32 + lq * 8;
            if (kb < 144) {
                int4 o0 = *(const int4*)&voff[c144 + kb];
                int4 o1 = *(const int4*)&voff[c144 + kb + 4];
                vfrag[ks][0] = (short)*(const unsigned short*)(vbase + o0.x);
                vfrag[ks][1] = (short)*(const unsigned short*)(vbase + o0.y);
                vfrag[ks][2] = (short)*(const unsigned short*)(vbase + o0.z);
                vfrag[ks][3] = (short)*(const unsigned short*)(vbase + o0.w);
                vfrag[ks][4] = (short)*(const unsigned short*)(vbase + o1.x);
                vfrag[ks][5] = (short)*(const unsigned short*)(vbase + o1.y);
                vfrag[ks][6] = (short)*(const unsigned short*)(vbase + o1.z);
                vfrag[ks][7] = (short)*(const unsigned short*)(vbase + o1.w);
            } else {
                vfrag[ks] = (bf16x8){0, 0, 0, 0, 0, 0, 0, 0};
            }
        }
        __syncthreads();   // B1: Ks ready (cc>0) / Qs+pads ready (cc==0); prev P reads drained

        const short* Bsrc = (cc == 0) ? Qs : Ks;
        // QK phase A: mt 0..4 (45 tiles), rows 0..79 of Ps
        for (int tt = w; tt < 45; tt += 16) {
            int mt = tt / 9, nt = tt - mt * 9;
            f32x4 c = {0.f, 0.f, 0.f, 0.f};
#pragma unroll
            for (int ks = 0; ks < 2; ks++) {
                bf16x8 a = *(const bf16x8*)&Qs[(mt * 16 + lm) * QSTR + ks * 32 + lq * 8];
                bf16x8 b = *(const bf16x8*)&Bsrc[(nt * 16 + lm) * QSTR + ks * 32 + lq * 8];
                c = __builtin_amdgcn_mfma_f32_16x16x32_bf16(a, b, c, 0, 0, 0);
            }
            float nfk = nfs[c144 + nt * 16 + lm];
#pragma unroll
            for (int r = 0; r < 4; r++) {
                int mrow = mt * 16 + lq * 4 + r;
                float p = __expf(fmaf(c[r], nfk, -qlen[mrow]));
                Ps[mrow * PSTR + nt * 16 + lm] = (short)f2b(p);
            }
        }
        __syncthreads();   // B2: P(A) ready

        // lsum phase A: waves 0..4 own row-tiles 0..4
        if (w < 5) {
#pragma unroll
            for (int ks = 0; ks < 5; ks++) {
                bf16x8 a = *(const bf16x8*)&Ps[(w * 16 + lm) * PSTR + ks * 32 + lq * 8];
                accL = __builtin_amdgcn_mfma_f32_16x16x32_bf16(a, (ks == 4) ? onesL : onesF, accL, 0, 0, 0);
            }
        }
        // PV phase A: mt 0..4
#pragma unroll
        for (int mt = 0; mt < 5; mt++) {
            f32x4 c = accO[mt];
#pragma unroll
            for (int ks = 0; ks < 5; ks++) {
                bf16x8 a = *(const bf16x8*)&Ps[(mt * 16 + lm) * PSTR + ks * 32 + lq * 8];
                c = __builtin_amdgcn_mfma_f32_16x16x32_bf16(a, vfrag[ks], c, 0, 0, 0);
            }
            accO[mt] = c;
        }
        __syncthreads();   // B3: P(A) reads drained — buffer reusable

        // QK phase B: mt 5..8 (36 tiles), buffer rows 0..63
        for (int tt = w; tt < 36; tt += 16) {
            int mt2 = tt / 9, nt = tt - mt2 * 9;
            int qrow0 = (mt2 + 5) * 16;
            f32x4 c = {0.f, 0.f, 0.f, 0.f};
#pragma unroll
            for (int ks = 0; ks < 2; ks++) {
                bf16x8 a = *(const bf16x8*)&Qs[(qrow0 + lm) * QSTR + ks * 32 + lq * 8];
                bf16x8 b = *(const bf16x8*)&Bsrc[(nt * 16 + lm) * QSTR + ks * 32 + lq * 8];
                c = __builtin_amdgcn_mfma_f32_16x16x32_bf16(a, b, c, 0, 0, 0);
            }
            float nfk = nfs[c144 + nt * 16 + lm];
#pragma unroll
            for (int r = 0; r < 4; r++) {
                int mrow = qrow0 + lq * 4 + r;               // global q row (qlen)
                float p = __expf(fmaf(c[r], nfk, -qlen[mrow]));
                Ps[(mt2 * 16 + lq * 4 + r) * PSTR + nt * 16 + lm] = (short)f2b(p);
            }
        }
        __syncthreads();   // B4: P(B) ready

        // lsum phase B: waves 5..8 own row-tiles 5..8 (buffer rows (w-5)*16..)
        if (w >= 5 && w < 9) {
#pragma unroll
            for (int ks = 0; ks < 5; ks++) {
                bf16x8 a = *(const bf16x8*)&Ps[((w - 5) * 16 + lm) * PSTR + ks * 32 + lq * 8];
                accL = __builtin_amdgcn_mfma_f32_16x16x32_bf16(a, (ks == 4) ? onesL : onesF, accL, 0, 0, 0);
            }
        }
        // PV phase B: mt 5..8 from buffer rows 0..63
#pragma unroll
        for (int mt2 = 0; mt2 < 4; mt2++) {
            f32x4 c = accO[mt2 + 5];
#pragma unroll
            for (int ks = 0; ks < 5; ks++) {
                bf16x8 a = *(const bf16x8*)&Ps[(mt2 * 16 + lm) * PSTR + ks * 32 + lq * 8];
                c = __builtin_amdgcn_mfma_f32_16x16x32_bf16(a, vfrag[ks], c, 0, 0, 0);
            }
            accO[mt2 + 5] = c;
        }
        // next chunk's B1 separates these P(B) reads from the next QK-A writes
    }

    if (w < 9 && lm == 0) {
#pragma unroll
        for (int r = 0; r < 4; r++) lsum[w * 16 + lq * 4 + r] = accL[r];
    }
    __syncthreads();
    if (tid < 144) {
        float l = lsum[tid];
        linv[tid] = 1.0f / l;
        bs[sbase + tIdx[tid]] = qlen[tid] + __logf(l);
    }
    __syncthreads();

#pragma unroll
    for (int mt = 0; mt < 9; mt++) {
        f32x4 c = accO[mt];
#pragma unroll
        for (int r = 0; r < 4; r++) {
            int mrow = mt * 16 + lq * 4 + r;
            Osort[(sbase + (size_t)k * CHK + mrow) * CHN + w * 16 + lm] = f2b(c[r] * linv[mrow]);
        }
    }
}

// ---------------------------------------------------------------- combine (4 hashes, inline softmax) + transpose + residual
__global__ __launch_bounds__(256) void combfin_k(
    const unsigned short* __restrict__ Osort, const float* __restrict__ bs,
    const int* __restrict__ undo, const float* __restrict__ inp, float* __restrict__ out)
{
    __shared__ float ac[32][260];
    __shared__ int   uS[4][32];
    __shared__ float pS[4][32];
    const int n = blockIdx.y;
    const int t0 = blockIdx.x * 32;
    const int tid = threadIdx.x;
    if (tid < 128) {
        int hh = tid >> 5, tt = tid & 31;
        size_t idx = (size_t)n * NJ + (size_t)hh * LL + t0 + tt;
        uS[hh][tt] = undo[idx];
        pS[hh][tt] = bs[idx];
    }
    __syncthreads();
    if (tid < 32) {
        float b0 = pS[0][tid], b1 = pS[1][tid], b2 = pS[2][tid], b3 = pS[3][tid];
        float mx = fmaxf(fmaxf(b0, b1), fmaxf(b2, b3));
        float e0 = __expf(b0 - mx), e1 = __expf(b1 - mx), e2 = __expf(b2 - mx), e3 = __expf(b3 - mx);
        float inv = 1.f / (e0 + e1 + e2 + e3);
        pS[0][tid] = e0 * inv; pS[1][tid] = e1 * inv; pS[2][tid] = e2 * inv; pS[3][tid] = e3 * inv;
    }
    __syncthreads();
    const int g = tid & 63, tq = tid >> 6;
    for (int tt8 = 0; tt8 < 8; tt8++) {
        int t = tq * 8 + tt8;
        float a0 = 0.f, a1 = 0.f, a2 = 0.f, a3 = 0.f;
#pragma unroll
        for (int hh = 0; hh < 4; hh++) {
            int row = uS[hh][t];
            float p = pS[hh][t];
            ushort4 u = *(const ushort4*)&Osort[((size_t)n * NJ + row) * CHN + g * 4];
            a0 = fmaf(p, b2f(u.x), a0);
            a1 = fmaf(p, b2f(u.y), a1);
            a2 = fmaf(p, b2f(u.z), a2);
            a3 = fmaf(p, b2f(u.w), a3);
        }
        *(float4*)&ac[t][g * 4] = make_float4(a0, a1, a2, a3);
    }
    __syncthreads();
    const int tp = tid & 31, er = tid >> 5;
    const float* inN = inp + (size_t)n * LL * CHN;
    float* outN = out + (size_t)n * LL * CHN;
    for (int it = 0; it < 32; it++) {
        int e = er + it * 8;
        size_t o = (size_t)e * LL + t0 + tp;
        outN[o] = ac[tp][e] * 0.1f + inN[o];
    }
}

// ---------------------------------------------------------------- launch
extern "C" void kernel_launch(void* const* d_in, const int* in_sizes, int n_in,
                              void* d_out, int out_size, void* d_ws, size_t ws_size,
                              hipStream_t stream)
{
    (void)in_sizes; (void)n_in; (void)out_size; (void)ws_size;
    const float* input   = (const float*)d_in[0];
    const float* w_match = (const float*)d_in[1];
    const float* b_match = (const float*)d_in[2];
    const float* w_asm   = (const float*)d_in[3];
    const float* b_asm   = (const float*)d_in[4];
    const float* rot     = (const float*)d_in[5];
    float* out = (float*)d_out;

    char* ws = (char*)d_ws;
    size_t off = 0;
    auto alloc = [&](size_t bytes) -> void* {
        void* p = ws + off;
        off += (bytes + 255) & ~(size_t)255;
        return p;
    };
    unsigned short* in_bf  = (unsigned short*)alloc((size_t)NB * LL * CHN * 2);   // = in_hi
    unsigned short* wT_bf  = (unsigned short*)alloc((size_t)9 * CHN * CHN * 2);
    unsigned short* ya_bf  = (unsigned short*)alloc((size_t)NB * LL * CHN * 2);
    unsigned short* yaT    = (unsigned short*)alloc((size_t)NB * LL * CHN * 2);
    float* xm     = (float*)alloc((size_t)NB * LL * CC * 4);
    float* xmT    = (float*)alloc((size_t)NB * LL * CC * 4);
    unsigned short* xmT_bf = (unsigned short*)alloc((size_t)NB * LL * CC * 2);
    float* ssq    = (float*)alloc((size_t)NB * LL * 4);
    int*   codes  = (int*)  alloc((size_t)NB * NJ * 4);
    int*   rank   = (int*)  alloc((size_t)NB * NJ * 4);
    int*   hist   = (int*)  alloc((size_t)NB * NJ * 4);
    int*   sidx   = (int*)  alloc((size_t)NB * NJ * 4);
    int*   undo   = (int*)  alloc((size_t)NB * NJ * 4);
    float* bs     = (float*)alloc((size_t)NB * NJ * 4);
    unsigned short* Osort = (unsigned short*)alloc((size_t)NB * NJ * CHN * 2);
    unsigned short* wmT_hi = (unsigned short*)alloc((size_t)9 * 64 * CHN * 2);
    unsigned short* wmT_lo = (unsigned short*)alloc((size_t)9 * 64 * CHN * 2);
    // in_lo (18.9 MB) aliases the head of Osort (75.5 MB): in_lo is written by
    // cvt_in_hilo_k and last read by conv_match_mfma_k, both strictly before
    // attn_mfma_k writes Osort on the same stream.
    unsigned short* in_lo = Osort;

    // input hi/lo split (hi also feeds the value-path conv)
    cvt_in_hilo_k<<<dim3(4608), 256, 0, stream>>>(input, in_bf, in_lo);
    // match path (split-bf16 MFMA — feeds hashing at ~fp32 precision)
    cvt_wm_hilo_k<<<dim3(8, 2, 9), 256, 0, stream>>>(w_match, wmT_hi, wmT_lo);
    conv_match_mfma_k<<<dim3(144, 1, NB), 256, 0, stream>>>(in_bf, in_lo, wmT_hi, wmT_lo, b_match, xm);
    transpose_k<<<dim3(288, 2, NB), 256, 0, stream>>>(xm, xmT, xmT_bf, CC, LL);
    // value path (bf16 MFMA)
    cvt_wT_k<<<dim3(8, 8, 9), 256, 0, stream>>>(w_asm, wT_bf);
    conv_mfma_k<<<dim3(72, 2, NB), 256, 0, stream>>>(in_bf, wT_bf, b_asm, ya_bf);
    transpose_bf_k<<<dim3(144, 4, NB), 256, 0, stream>>>(ya_bf, yaT);
    // hashing + sort
    hash_k<<<dim3(144, NHASH), 256, 0, stream>>>(xmT, rot, codes, ssq);
    sort_hist_k<<<dim3(144, NB), 256, 0, stream>>>(codes, hist, rank);
    sort_scan_k<<<dim3(NB), 256, 0, stream>>>(hist);
    sort_scatter_k<<<dim3(144, NB), 256, 0, stream>>>(codes, rank, hist, sidx, undo);
    // attention + combine
    attn_mfma_k<<<dim3(NCHUNK, NHASH, NB), 1024, 0, stream>>>(xmT_bf, yaT, ssq, sidx, Osort, bs);
    combfin_k<<<dim3(288, NB), 256, 0, stream>>>(Osort, bs, undo, input, out);
}

// Round 10
// 455.327 us; speedup vs baseline: 1.2532x; 1.2532x over previous
//
#include <hip/hip_runtime.h>
#include <cstdint>
#include <cstddef>

#define NB 4
#define HH 96
#define WW 96
#define CHN 256
#define CC 64
#define LL 9216
#define NHASH 4
#define HBK 64
#define CHK 144
#define NCHUNK 64
#define NJ 36864   // NHASH * LL

typedef __attribute__((ext_vector_type(8))) short bf16x8;
typedef __attribute__((ext_vector_type(8))) unsigned short u16x8;
typedef __attribute__((ext_vector_type(4))) float f32x4;

__device__ __forceinline__ unsigned short f2b(float f) {
    unsigned int x = __float_as_uint(f);
    x += 0x7FFFu + ((x >> 16) & 1u);
    return (unsigned short)(x >> 16);
}
__device__ __forceinline__ float b2f(unsigned short u) {
    return __uint_as_float(((unsigned int)u) << 16);
}

// ---------------------------------------------------------------- input fp32 -> bf16 hi + bf16 lo residual
__global__ __launch_bounds__(256) void cvt_in_hilo_k(const float* __restrict__ in,
                                                     unsigned short* __restrict__ hi,
                                                     unsigned short* __restrict__ lo)
{
    size_t g = ((size_t)blockIdx.x * 256 + threadIdx.x) * 8;
    float4 v0 = *(const float4*)(in + g);
    float4 v1 = *(const float4*)(in + g + 4);
    float xs[8] = {v0.x, v0.y, v0.z, v0.w, v1.x, v1.y, v1.z, v1.w};
    u16x8 h, l;
#pragma unroll
    for (int i = 0; i < 8; i++) {
        unsigned short hv = f2b(xs[i]);
        h[i] = hv;
        l[i] = f2b(xs[i] - b2f(hv));
    }
    *(u16x8*)(hi + g) = h;
    *(u16x8*)(lo + g) = l;
}

// ---------------------------------------------------------------- w_match [tap][ci][64] fp32 -> wmT [tap][co=64][ci=256] bf16 hi/lo
__global__ __launch_bounds__(256) void cvt_wm_hilo_k(const float* __restrict__ w,
                                                     unsigned short* __restrict__ hiT,
                                                     unsigned short* __restrict__ loT)
{
    __shared__ float tl[32][33];
    const int tap = blockIdx.z;
    const int c0 = blockIdx.x * 32;   // ci
    const int o0 = blockIdx.y * 32;   // co
    const int tx = threadIdx.x & 31, ty0 = threadIdx.x >> 5;
#pragma unroll
    for (int i = 0; i < 32; i += 8)
        tl[ty0 + i][tx] = w[((size_t)tap * 256 + c0 + ty0 + i) * 64 + o0 + tx];
    __syncthreads();
#pragma unroll
    for (int i = 0; i < 32; i += 8) {
        float v = tl[tx][ty0 + i];
        unsigned short h = f2b(v);
        size_t o = ((size_t)tap * 64 + o0 + ty0 + i) * 256 + c0 + tx;
        hiT[o] = h;
        loT[o] = f2b(v - b2f(h));
    }
}

// ---------------------------------------------------------------- MFMA conv 3x3 (match path, split-bf16 ~fp32 precision)
// v4: ci-step widened 32 -> 64. Halves barrier pairs (72 -> 36 per block); the
// barrier drain (all waves wait on LDS-write completion) was paid once per 32-ci
// step. Row stride 72 shorts = 36 dwords = 4 mod 32 banks -> frag reads only
// alias lm/lm+8 (2-way = free). LDS 4 x 64 x 72 x 2B = 36.9KB.
#define ASTR2 72
__global__ __launch_bounds__(256, 2) void conv_match_mfma_k(
    const unsigned short* __restrict__ in_hi, const unsigned short* __restrict__ in_lo,
    const unsigned short* __restrict__ wmT_hi, const unsigned short* __restrict__ wmT_lo,
    const float* __restrict__ bias, float* __restrict__ xm)
{
    __shared__ short Ah[64 * ASTR2], Al[64 * ASTR2];
    __shared__ short Bh[64 * ASTR2], Bl[64 * ASTR2];
    const int n = blockIdx.z, p0 = blockIdx.x * 64;
    const int tid = threadIdx.x;
    const int w = tid >> 6;
    const int lane = tid & 63, lm = lane & 15, lq = lane >> 4;
    const int r = tid >> 2, q8 = (tid & 3) * 8;      // staging: row 0..63, 8-short quarter per half
    const int p = p0 + r, py = p / WW, px = p % WW;
    const unsigned short* hiN = in_hi + (size_t)n * LL * CHN;
    const unsigned short* loN = in_lo + (size_t)n * LL * CHN;

    f32x4 acc[4];
#pragma unroll
    for (int b = 0; b < 4; b++) acc[b] = (f32x4){0.f, 0.f, 0.f, 0.f};

    for (int tap = 0; tap < 9; tap++) {
        const int ky = tap / 3, kx = tap - ky * 3;
        const int sy = py + ky - 1, sx = px + kx - 1;
        const bool valid = ((unsigned)sy < HH) && ((unsigned)sx < WW);
        const unsigned short* ah = hiN + (size_t)(sy * WW + sx) * CHN + q8;
        const unsigned short* al = loN + (size_t)(sy * WW + sx) * CHN + q8;
        const unsigned short* bh = wmT_hi + ((size_t)tap * 64 + r) * 256 + q8;
        const unsigned short* bl = wmT_lo + ((size_t)tap * 64 + r) * 256 + q8;
        for (int ci0 = 0; ci0 < 256; ci0 += 64) {
            u16x8 avh0 = (u16x8){0,0,0,0,0,0,0,0}, avh1 = (u16x8){0,0,0,0,0,0,0,0};
            u16x8 avl0 = (u16x8){0,0,0,0,0,0,0,0}, avl1 = (u16x8){0,0,0,0,0,0,0,0};
            if (valid) {
                avh0 = *(const u16x8*)(ah + ci0);
                avh1 = *(const u16x8*)(ah + ci0 + 32);
                avl0 = *(const u16x8*)(al + ci0);
                avl1 = *(const u16x8*)(al + ci0 + 32);
            }
            u16x8 bvh0 = *(const u16x8*)(bh + ci0);
            u16x8 bvh1 = *(const u16x8*)(bh + ci0 + 32);
            u16x8 bvl0 = *(const u16x8*)(bl + ci0);
            u16x8 bvl1 = *(const u16x8*)(bl + ci0 + 32);
            __syncthreads();
            *(u16x8*)&Ah[r * ASTR2 + q8]      = avh0;
            *(u16x8*)&Ah[r * ASTR2 + q8 + 32] = avh1;
            *(u16x8*)&Al[r * ASTR2 + q8]      = avl0;
            *(u16x8*)&Al[r * ASTR2 + q8 + 32] = avl1;
            *(u16x8*)&Bh[r * ASTR2 + q8]      = bvh0;
            *(u16x8*)&Bh[r * ASTR2 + q8 + 32] = bvh1;
            *(u16x8*)&Bl[r * ASTR2 + q8]      = bvl0;
            *(u16x8*)&Bl[r * ASTR2 + q8 + 32] = bvl1;
            __syncthreads();
#pragma unroll
            for (int cs = 0; cs < 2; cs++) {
                bf16x8 afh = *(const bf16x8*)&Ah[(w * 16 + lm) * ASTR2 + cs * 32 + lq * 8];
                bf16x8 afl = *(const bf16x8*)&Al[(w * 16 + lm) * ASTR2 + cs * 32 + lq * 8];
#pragma unroll
                for (int nt = 0; nt < 4; nt++) {
                    bf16x8 bfh = *(const bf16x8*)&Bh[(nt * 16 + lm) * ASTR2 + cs * 32 + lq * 8];
                    bf16x8 bfl = *(const bf16x8*)&Bl[(nt * 16 + lm) * ASTR2 + cs * 32 + lq * 8];
                    acc[nt] = __builtin_amdgcn_mfma_f32_16x16x32_bf16(afh, bfh, acc[nt], 0, 0, 0);
                    acc[nt] = __builtin_amdgcn_mfma_f32_16x16x32_bf16(afh, bfl, acc[nt], 0, 0, 0);
                    acc[nt] = __builtin_amdgcn_mfma_f32_16x16x32_bf16(afl, bfh, acc[nt], 0, 0, 0);
                }
            }
        }
    }
    float bvv[4];
#pragma unroll
    for (int nt = 0; nt < 4; nt++) bvv[nt] = bias[nt * 16 + lm];
    float* outN = xm + (size_t)n * LL * 64;
#pragma unroll
    for (int r4 = 0; r4 < 4; r4++) {
        int row = p0 + w * 16 + lq * 4 + r4;
        float* od = outN + (size_t)row * 64;
#pragma unroll
        for (int nt = 0; nt < 4; nt++)
            od[nt * 16 + lm] = acc[nt][r4] + bvv[nt];
    }
}

// ---------------------------------------------------------------- fp32 transpose (match embedding) + bf16 copy
__global__ __launch_bounds__(256) void transpose_k(const float* __restrict__ in, float* __restrict__ out,
                                                   unsigned short* __restrict__ out_bf, int R, int Cc)
{
    __shared__ float tl[32][33];
    const int n = blockIdx.z;
    const size_t base = (size_t)n * R * Cc;
    int c0 = blockIdx.x * 32, r0 = blockIdx.y * 32;
    int tx = threadIdx.x & 31, ty0 = threadIdx.x >> 5;
#pragma unroll
    for (int i = 0; i < 32; i += 8)
        tl[ty0 + i][tx] = in[base + (size_t)(r0 + ty0 + i) * Cc + c0 + tx];
    __syncthreads();
#pragma unroll
    for (int i = 0; i < 32; i += 8) {
        float v = tl[tx][ty0 + i];
        size_t o = base + (size_t)(c0 + ty0 + i) * R + r0 + tx;
        out[o] = v;
        out_bf[o] = f2b(v);
    }
}

// ---------------------------------------------------------------- w_asm [tap][ci][co] fp32 -> wT [tap][co][ci] bf16
__global__ __launch_bounds__(256) void cvt_wT_k(const float* __restrict__ w, unsigned short* __restrict__ wT)
{
    __shared__ float tl[32][33];
    const int tap = blockIdx.z;
    const int c0 = blockIdx.x * 32;
    const int o0 = blockIdx.y * 32;
    const int tx = threadIdx.x & 31, ty0 = threadIdx.x >> 5;
#pragma unroll
    for (int i = 0; i < 32; i += 8)
        tl[ty0 + i][tx] = w[((size_t)tap * 256 + c0 + ty0 + i) * 256 + o0 + tx];
    __syncthreads();
#pragma unroll
    for (int i = 0; i < 32; i += 8)
        wT[((size_t)tap * 256 + o0 + ty0 + i) * 256 + c0 + tx] = f2b(tl[tx][ty0 + i]);
}

// ---------------------------------------------------------------- MFMA conv 3x3 (value path, bf16)
// v3: ci-step widened 32 -> 64 (barrier pairs 72 -> 36). Row stride 72 shorts:
// frag reads alias only lm/lm+8 (2-way = free). LDS 2 x 128 x 72 x 2B = 36.9KB.
__global__ __launch_bounds__(256) void conv_mfma_k(
    const unsigned short* __restrict__ in_bf, const unsigned short* __restrict__ wT,
    const float* __restrict__ bias, unsigned short* __restrict__ ya_bf)
{
    __shared__ short As[128 * ASTR2];
    __shared__ short Bs[128 * ASTR2];
    const int n = blockIdx.z, p0 = blockIdx.x * 128, co0 = blockIdx.y * 128;
    const int tid = threadIdx.x;
    const int w = tid >> 6, wr = w >> 1, wc = w & 1;
    const int lane = tid & 63, lm = lane & 15, lq = lane >> 4;
    const int r = tid >> 1, hf = tid & 1;            // staging: row 0..127, 32-short half
    const int p = p0 + r, py = p / WW, px = p % WW;
    const unsigned short* inN = in_bf + (size_t)n * LL * CHN;

    f32x4 acc[4][4];
#pragma unroll
    for (int a = 0; a < 4; a++)
#pragma unroll
        for (int b = 0; b < 4; b++) acc[a][b] = (f32x4){0.f, 0.f, 0.f, 0.f};

    for (int tap = 0; tap < 9; tap++) {
        const int ky = tap / 3, kx = tap - ky * 3;
        const int sy = py + ky - 1, sx = px + kx - 1;
        const bool valid = ((unsigned)sy < HH) && ((unsigned)sx < WW);
        const unsigned short* asrc = inN + (size_t)(sy * WW + sx) * CHN + hf * 32;
        const unsigned short* bsrc = wT + ((size_t)tap * 256 + co0 + r) * 256 + hf * 32;
        for (int ci0 = 0; ci0 < 256; ci0 += 64) {
            u16x8 av0 = (u16x8){0,0,0,0,0,0,0,0}, av1 = (u16x8){0,0,0,0,0,0,0,0};
            u16x8 av2 = (u16x8){0,0,0,0,0,0,0,0}, av3 = (u16x8){0,0,0,0,0,0,0,0};
            if (valid) {
                av0 = *(const u16x8*)(asrc + ci0);
                av1 = *(const u16x8*)(asrc + ci0 + 8);
                av2 = *(const u16x8*)(asrc + ci0 + 16);
                av3 = *(const u16x8*)(asrc + ci0 + 24);
            }
            u16x8 bv0 = *(const u16x8*)(bsrc + ci0);
            u16x8 bv1 = *(const u16x8*)(bsrc + ci0 + 8);
            u16x8 bv2 = *(const u16x8*)(bsrc + ci0 + 16);
            u16x8 bv3 = *(const u16x8*)(bsrc + ci0 + 24);
            __syncthreads();
            *(u16x8*)&As[r * ASTR2 + hf * 32]      = av0;
            *(u16x8*)&As[r * ASTR2 + hf * 32 + 8]  = av1;
            *(u16x8*)&As[r * ASTR2 + hf * 32 + 16] = av2;
            *(u16x8*)&As[r * ASTR2 + hf * 32 + 24] = av3;
            *(u16x8*)&Bs[r * ASTR2 + hf * 32]      = bv0;
            *(u16x8*)&Bs[r * ASTR2 + hf * 32 + 8]  = bv1;
            *(u16x8*)&Bs[r * ASTR2 + hf * 32 + 16] = bv2;
            *(u16x8*)&Bs[r * ASTR2 + hf * 32 + 24] = bv3;
            __syncthreads();
#pragma unroll
            for (int cs = 0; cs < 2; cs++) {
                bf16x8 af[4], bf[4];
#pragma unroll
                for (int mt = 0; mt < 4; mt++)
                    af[mt] = *(const bf16x8*)&As[(wr * 64 + mt * 16 + lm) * ASTR2 + cs * 32 + lq * 8];
#pragma unroll
                for (int nt = 0; nt < 4; nt++)
                    bf[nt] = *(const bf16x8*)&Bs[(wc * 64 + nt * 16 + lm) * ASTR2 + cs * 32 + lq * 8];
#pragma unroll
                for (int mt = 0; mt < 4; mt++)
#pragma unroll
                    for (int nt = 0; nt < 4; nt++)
                        acc[mt][nt] = __builtin_amdgcn_mfma_f32_16x16x32_bf16(af[mt], bf[nt], acc[mt][nt], 0, 0, 0);
            }
        }
    }
    float bv[4];
#pragma unroll
    for (int nt = 0; nt < 4; nt++) bv[nt] = bias[co0 + wc * 64 + nt * 16 + lm];
#pragma unroll
    for (int mt = 0; mt < 4; mt++) {
#pragma unroll
        for (int r4 = 0; r4 < 4; r4++) {
            int row = p0 + wr * 64 + mt * 16 + lq * 4 + r4;
            unsigned short* od = ya_bf + ((size_t)n * LL + row) * CHN + co0 + wc * 64;
#pragma unroll
            for (int nt = 0; nt < 4; nt++)
                od[nt * 16 + lm] = f2b(acc[mt][nt][r4] + bv[nt]);
        }
    }
}

// ---------------------------------------------------------------- bf16 transpose: ya_bf (viewed [256][9216]) -> yaT [9216][256]
__global__ __launch_bounds__(256) void transpose_bf_k(const unsigned short* __restrict__ in,
                                                      unsigned short* __restrict__ out)
{
    __shared__ unsigned short tl[64][65];
    const int n = blockIdx.z;
    const size_t base = (size_t)n * LL * CHN;
    const int t0 = blockIdx.x * 64, e0 = blockIdx.y * 64;
    const int tx = threadIdx.x & 63, ty0 = threadIdx.x >> 6;
#pragma unroll
    for (int i = 0; i < 16; i++) {
        int row = ty0 + i * 4;
        tl[row][tx] = in[base + (size_t)(e0 + row) * LL + t0 + tx];
    }
    __syncthreads();
#pragma unroll
    for (int i = 0; i < 16; i++) {
        int row = ty0 + i * 4;
        out[base + (size_t)(t0 + row) * CHN + e0 + tx] = tl[tx][row];
    }
}

// ---------------------------------------------------------------- hashing: codes + squared norms (fp32!)
__global__ __launch_bounds__(256) void hash_k(const float* __restrict__ xmT, const float* __restrict__ rot,
                                              int* __restrict__ codes, float* __restrict__ ssq)
{
    __shared__ float rs[32 * 68];   // [i][f], stride 68, this block's hash only
    const int h = blockIdx.y;
    for (int e = threadIdx.x; e < 2048; e += 256) {
        int hi = e >> 6, f = e & 63;
        rs[hi * 68 + f] = rot[f * 128 + h * 32 + hi];
    }
    __syncthreads();
    int g = blockIdx.x * 256 + threadIdx.x;
    int n = g / LL, t = g % LL;
    float4 x4[16];
    const float* src = xmT + (size_t)g * CC;
#pragma unroll
    for (int f4 = 0; f4 < 16; f4++) x4[f4] = *(const float4*)(src + f4 * 4);
    if (h == 0) {
        float ss = 0.f;
#pragma unroll
        for (int f4 = 0; f4 < 16; f4++)
            ss += x4[f4].x * x4[f4].x + x4[f4].y * x4[f4].y + x4[f4].z * x4[f4].z + x4[f4].w * x4[f4].w;
        ssq[g] = ss;
    }
    float bp = -1e30f, bn = -1e30f;
    int ip = 0, inn = 0;
    for (int i = 0; i < 32; i++) {
        const float* rr = &rs[i * 68];
        float d0 = 0.f, d1 = 0.f, d2 = 0.f, d3 = 0.f;
#pragma unroll
        for (int f4 = 0; f4 < 16; f4++) {
            float4 r4 = *(const float4*)(rr + f4 * 4);
            d0 = fmaf(x4[f4].x, r4.x, d0);
            d1 = fmaf(x4[f4].y, r4.y, d1);
            d2 = fmaf(x4[f4].z, r4.z, d2);
            d3 = fmaf(x4[f4].w, r4.w, d3);
        }
        float d = (d0 + d1) + (d2 + d3);
        if (d > bp) { bp = d; ip = i; }
        if (-d > bn) { bn = -d; inn = i; }
    }
    int code = (bp >= bn) ? ip : (32 + inn);
    codes[(size_t)n * NJ + h * LL + t] = code + h * HBK;
}

// ---------------------------------------------------------------- stable counting sort (256 buckets)
__global__ __launch_bounds__(256) void sort_hist_k(const int* __restrict__ codes, int* __restrict__ hist,
                                                   int* __restrict__ rank)
{
    __shared__ int lhw[4][256];
    const int n = blockIdx.y, seg = blockIdx.x, tid = threadIdx.x;
    const int w = tid >> 6, lane = tid & 63;
    int j = seg * 256 + tid;
    int c = codes[(size_t)n * NJ + j];
    for (int e = tid; e < 1024; e += 256) ((int*)lhw)[e] = 0;
    __syncthreads();
    unsigned long long eq = ~0ull;
#pragma unroll
    for (int b = 0; b < 8; b++) {
        unsigned long long m = __ballot((c >> b) & 1);
        eq &= ((c >> b) & 1) ? m : ~m;
    }
    int rw = __popcll(eq & ((1ull << lane) - 1ull));   // rank within wave (tid order)
    int cntw = __popcll(eq);                           // class count in this wave
    if (rw == 0) lhw[w][c] = cntw;                     // unique (w,c) writer
    __syncthreads();
    int base = 0;
    if (w > 0) base += lhw[0][c];
    if (w > 1) base += lhw[1][c];
    if (w > 2) base += lhw[2][c];
    rank[(size_t)n * NJ + j] = base + rw;
    hist[(size_t)n * NJ + tid * 144 + seg] = lhw[0][tid] + lhw[1][tid] + lhw[2][tid] + lhw[3][tid];
}

__global__ __launch_bounds__(256) void sort_scan_k(int* __restrict__ hist)
{
    const int n = blockIdx.x;
    const int key = threadIdx.x;
    int* hn = hist + (size_t)n * NJ;
    int sum = 0;
    for (int s = 0; s < 144; s++) sum += hn[key * 144 + s];
    __shared__ int sc[256];
    sc[key] = sum;
    __syncthreads();
    for (int off = 1; off < 256; off <<= 1) {
        int v = (key >= off) ? sc[key - off] : 0;
        __syncthreads();
        sc[key] += v;
        __syncthreads();
    }
    int run = sc[key] - sum;   // exclusive prefix
    for (int s = 0; s < 144; s++) { int v = hn[key * 144 + s]; hn[key * 144 + s] = run; run += v; }
}

__global__ __launch_bounds__(256) void sort_scatter_k(const int* __restrict__ codes, const int* __restrict__ rank,
                                                      const int* __restrict__ hist, int* __restrict__ sidx,
                                                      int* __restrict__ undo)
{
    const int n = blockIdx.y, seg = blockIdx.x, tid = threadIdx.x;
    int j = seg * 256 + tid;
    int c = codes[(size_t)n * NJ + j];
    int dest = hist[(size_t)n * NJ + c * 144 + seg] + rank[(size_t)n * NJ + j];
    sidx[(size_t)n * NJ + dest] = j;
    undo[(size_t)n * NJ + j] = dest;
}

// ---------------------------------------------------------------- MFMA attention v5 (verified at 124us; v6's split-P
// reverted — 2 blocks/CU needs total regs <= 64 incl. AGPRs, but live state is ~90+ -> guaranteed spills, measured
// 577MB scratch writes. 1 block/CU with full 144-row Ps is this structure's register-feasible optimum.)
#define QSTR 72     // Q/K row stride in shorts
#define PSTR 164    // P row stride in shorts (conflict-free write quadrants)
__global__ __launch_bounds__(1024, 4) __attribute__((amdgpu_waves_per_eu(4, 4))) void attn_mfma_k(
    const unsigned short* __restrict__ xmT_bf, const unsigned short* __restrict__ yaT,
    const float* __restrict__ ssq, const int* __restrict__ sidx,
    unsigned short* __restrict__ Osort, float* __restrict__ bs)
{
    __shared__ short Qs[144 * QSTR];
    __shared__ short Ks[144 * QSTR];
    __shared__ short Ps[144 * PSTR];
    __shared__ int   tIdx[432];
    __shared__ int   voff[432];
    __shared__ float nfs[432];
    __shared__ float qlen[432];
    __shared__ float lsum[144];
    __shared__ float linv[144];

    const int k = blockIdx.x, h = blockIdx.y, n = blockIdx.z;
    const int tid = threadIdx.x;
    const int w = tid >> 6, lane = tid & 63;
    const int lm = lane & 15, lq = lane >> 4;
    const size_t sbase = (size_t)n * NJ + (size_t)h * LL;

    if (tid < 432) {
        int cc = tid / CHK, rr = tid - cc * CHK;
        int c = (cc == 0) ? k : (cc == 1 ? (k + NCHUNK - 1) & (NCHUNK - 1) : (k + 1) & (NCHUNK - 1));
        int j = sidx[sbase + c * CHK + rr];
        int t = j % LL;
        tIdx[tid] = t;
        voff[tid] = t * (CHN * 2);
        float m = fmaxf(ssq[(size_t)n * LL + t], 5e-5f);
        float nf = rsqrtf(m);
        nfs[tid] = nf;
        qlen[tid] = m * nf;   // sqrt(m) = |q| clamped
    }
    __syncthreads();   // tIdx/voff/nfs/qlen ready

    // stage Q rows (raw bf16)
    const int sr = tid >> 3, sj = (tid & 7) * 8;
    const int sr2 = (tid + 1024) >> 3, sj2 = (tid & 7) * 8;
    {
        u16x8 v = *(const u16x8*)(xmT_bf + ((size_t)n * LL + tIdx[sr]) * CC + sj);
        *(u16x8*)&Qs[sr * QSTR + sj] = v;
        if (tid < 128) {
            u16x8 v2 = *(const u16x8*)(xmT_bf + ((size_t)n * LL + tIdx[sr2]) * CC + sj2);
            *(u16x8*)&Qs[sr2 * QSTR + sj2] = v2;
        }
    }
    // zero P pad columns 144..159 once (P writes later touch cols 0..143 only)
    for (int e = tid; e < 2304; e += 1024) {
        int r = e >> 4, c = 144 + (e & 15);
        Ps[r * PSTR + c] = 0;
    }
    // T14: issue chunk-1 K loads into registers now (consumed at top of chunk 1)
    u16x8 kreg0, kreg1;
    kreg0 = *(const u16x8*)(xmT_bf + ((size_t)n * LL + tIdx[CHK + sr]) * CC + sj);
    if (tid < 128)
        kreg1 = *(const u16x8*)(xmT_bf + ((size_t)n * LL + tIdx[CHK + sr2]) * CC + sj2);

    const char* vbase = (const char*)(yaT + (size_t)n * LL * CHN + w * 16 + lm);
    f32x4 accO[9];
#pragma unroll
    for (int mt = 0; mt < 9; mt++) accO[mt] = (f32x4){0.f, 0.f, 0.f, 0.f};
    f32x4 accL = (f32x4){0.f, 0.f, 0.f, 0.f};
    bf16x8 onesF, onesL;
#pragma unroll
    for (int i = 0; i < 8; i++) {
        onesF[i] = (short)0x3F80;
        onesL[i] = (lq < 2) ? (short)0x3F80 : (short)0;   // mask pad keys 144..159 (k-step 4, lq>=2)
    }

    for (int cc = 0; cc < 3; cc++) {
        const int c144 = cc * CHK;
        if (cc > 0) {
            *(u16x8*)&Ks[sr * QSTR + sj] = kreg0;
            if (tid < 128) *(u16x8*)&Ks[sr2 * QSTR + sj2] = kreg1;
        }
        if (cc < 2) {
            kreg0 = *(const u16x8*)(xmT_bf + ((size_t)n * LL + tIdx[(cc + 1) * CHK + sr]) * CC + sj);
            if (tid < 128)
                kreg1 = *(const u16x8*)(xmT_bf + ((size_t)n * LL + tIdx[(cc + 1) * CHK + sr2]) * CC + sj2);
        }
        // V B-frag gathers from global — issued early, consumed after QK (latency hidden)
        bf16x8 vfrag[5];
#pragma unroll
        for (int ks = 0; ks < 5; ks++) {
            int kb = ks * 32 + lq * 8;
            if (kb < 144) {
                int4 o0 = *(const int4*)&voff[c144 + kb];
                int4 o1 = *(const int4*)&voff[c144 + kb + 4];
                vfrag[ks][0] = (short)*(const unsigned short*)(vbase + o0.x);
                vfrag[ks][1] = (short)*(const unsigned short*)(vbase + o0.y);
                vfrag[ks][2] = (short)*(const unsigned short*)(vbase + o0.z);
                vfrag[ks][3] = (short)*(const unsigned short*)(vbase + o0.w);
                vfrag[ks][4] = (short)*(const unsigned short*)(vbase + o1.x);
                vfrag[ks][5] = (short)*(const unsigned short*)(vbase + o1.y);
                vfrag[ks][6] = (short)*(const unsigned short*)(vbase + o1.z);
                vfrag[ks][7] = (short)*(const unsigned short*)(vbase + o1.w);
            } else {
                vfrag[ks] = (bf16x8){0, 0, 0, 0, 0, 0, 0, 0};
            }
        }
        __syncthreads();

        // QK (B^T GEMM) + exp; raw scores post-scaled by key norm; P written straight to LDS
        const short* Bsrc = (cc == 0) ? Qs : Ks;
        for (int tt = w; tt < 81; tt += 16) {
            int mt = tt / 9, nt = tt - mt * 9;
            f32x4 c = {0.f, 0.f, 0.f, 0.f};
#pragma unroll
            for (int ks = 0; ks < 2; ks++) {
                bf16x8 a = *(const bf16x8*)&Qs[(mt * 16 + lm) * QSTR + ks * 32 + lq * 8];
                bf16x8 b = *(const bf16x8*)&Bsrc[(nt * 16 + lm) * QSTR + ks * 32 + lq * 8];
                c = __builtin_amdgcn_mfma_f32_16x16x32_bf16(a, b, c, 0, 0, 0);
            }
            float nfk = nfs[c144 + nt * 16 + lm];
#pragma unroll
            for (int r = 0; r < 4; r++) {
                int mrow = mt * 16 + lq * 4 + r;
                float p = __expf(fmaf(c[r], nfk, -qlen[mrow]));
                Ps[mrow * PSTR + nt * 16 + lm] = (short)f2b(p);
            }
        }
        __syncthreads();   // Ps ready (pad cols are permanent zeros)

        // lsum via ones-MFMA (waves 0..8, mt = w)
        if (w < 9) {
#pragma unroll
            for (int ks = 0; ks < 5; ks++) {
                bf16x8 a = *(const bf16x8*)&Ps[(w * 16 + lm) * PSTR + ks * 32 + lq * 8];
                accL = __builtin_amdgcn_mfma_f32_16x16x32_bf16(a, (ks == 4) ? onesL : onesF, accL, 0, 0, 0);
            }
        }
        // PV: 9 m-tiles, V frags in registers
#pragma unroll
        for (int mt = 0; mt < 9; mt++) {
            f32x4 c = accO[mt];
#pragma unroll
            for (int ks = 0; ks < 5; ks++) {
                bf16x8 a = *(const bf16x8*)&Ps[(mt * 16 + lm) * PSTR + ks * 32 + lq * 8];
                c = __builtin_amdgcn_mfma_f32_16x16x32_bf16(a, vfrag[ks], c, 0, 0, 0);
            }
            accO[mt] = c;
        }
    }

    if (w < 9 && lm == 0) {
#pragma unroll
        for (int r = 0; r < 4; r++) lsum[w * 16 + lq * 4 + r] = accL[r];
    }
    __syncthreads();
    if (tid < 144) {
        float l = lsum[tid];
        linv[tid] = 1.0f / l;
        bs[sbase + tIdx[tid]] = qlen[tid] + __logf(l);
    }
    __syncthreads();

#pragma unroll
    for (int mt = 0; mt < 9; mt++) {
        f32x4 c = accO[mt];
#pragma unroll
        for (int r = 0; r < 4; r++) {
            int mrow = mt * 16 + lq * 4 + r;
            Osort[(sbase + (size_t)k * CHK + mrow) * CHN + w * 16 + lm] = f2b(c[r] * linv[mrow]);
        }
    }
}

// ---------------------------------------------------------------- combine (4 hashes, inline softmax) + transpose + residual
__global__ __launch_bounds__(256) void combfin_k(
    const unsigned short* __restrict__ Osort, const float* __restrict__ bs,
    const int* __restrict__ undo, const float* __restrict__ inp, float* __restrict__ out)
{
    __shared__ float ac[32][260];
    __shared__ int   uS[4][32];
    __shared__ float pS[4][32];
    const int n = blockIdx.y;
    const int t0 = blockIdx.x * 32;
    const int tid = threadIdx.x;
    if (tid < 128) {
        int hh = tid >> 5, tt = tid & 31;
        size_t idx = (size_t)n * NJ + (size_t)hh * LL + t0 + tt;
        uS[hh][tt] = undo[idx];
        pS[hh][tt] = bs[idx];
    }
    __syncthreads();
    if (tid < 32) {
        float b0 = pS[0][tid], b1 = pS[1][tid], b2 = pS[2][tid], b3 = pS[3][tid];
        float mx = fmaxf(fmaxf(b0, b1), fmaxf(b2, b3));
        float e0 = __expf(b0 - mx), e1 = __expf(b1 - mx), e2 = __expf(b2 - mx), e3 = __expf(b3 - mx);
        float inv = 1.f / (e0 + e1 + e2 + e3);
        pS[0][tid] = e0 * inv; pS[1][tid] = e1 * inv; pS[2][tid] = e2 * inv; pS[3][tid] = e3 * inv;
    }
    __syncthreads();
    const int g = tid & 63, tq = tid >> 6;
    for (int tt8 = 0; tt8 < 8; tt8++) {
        int t = tq * 8 + tt8;
        float a0 = 0.f, a1 = 0.f, a2 = 0.f, a3 = 0.f;
#pragma unroll
        for (int hh = 0; hh < 4; hh++) {
            int row = uS[hh][t];
            float p = pS[hh][t];
            ushort4 u = *(const ushort4*)&Osort[((size_t)n * NJ + row) * CHN + g * 4];
            a0 = fmaf(p, b2f(u.x), a0);
            a1 = fmaf(p, b2f(u.y), a1);
            a2 = fmaf(p, b2f(u.z), a2);
            a3 = fmaf(p, b2f(u.w), a3);
        }
        *(float4*)&ac[t][g * 4] = make_float4(a0, a1, a2, a3);
    }
    __syncthreads();
    const int tp = tid & 31, er = tid >> 5;
    const float* inN = inp + (size_t)n * LL * CHN;
    float* outN = out + (size_t)n * LL * CHN;
    for (int it = 0; it < 32; it++) {
        int e = er + it * 8;
        size_t o = (size_t)e * LL + t0 + tp;
        outN[o] = ac[tp][e] * 0.1f + inN[o];
    }
}

// ---------------------------------------------------------------- launch
extern "C" void kernel_launch(void* const* d_in, const int* in_sizes, int n_in,
                              void* d_out, int out_size, void* d_ws, size_t ws_size,
                              hipStream_t stream)
{
    (void)in_sizes; (void)n_in; (void)out_size; (void)ws_size;
    const float* input   = (const float*)d_in[0];
    const float* w_match = (const float*)d_in[1];
    const float* b_match = (const float*)d_in[2];
    const float* w_asm   = (const float*)d_in[3];
    const float* b_asm   = (const float*)d_in[4];
    const float* rot     = (const float*)d_in[5];
    float* out = (float*)d_out;

    char* ws = (char*)d_ws;
    size_t off = 0;
    auto alloc = [&](size_t bytes) -> void* {
        void* p = ws + off;
        off += (bytes + 255) & ~(size_t)255;
        return p;
    };
    unsigned short* in_bf  = (unsigned short*)alloc((size_t)NB * LL * CHN * 2);   // = in_hi
    unsigned short* wT_bf  = (unsigned short*)alloc((size_t)9 * CHN * CHN * 2);
    unsigned short* ya_bf  = (unsigned short*)alloc((size_t)NB * LL * CHN * 2);
    unsigned short* yaT    = (unsigned short*)alloc((size_t)NB * LL * CHN * 2);
    float* xm     = (float*)alloc((size_t)NB * LL * CC * 4);
    float* xmT    = (float*)alloc((size_t)NB * LL * CC * 4);
    unsigned short* xmT_bf = (unsigned short*)alloc((size_t)NB * LL * CC * 2);
    float* ssq    = (float*)alloc((size_t)NB * LL * 4);
    int*   codes  = (int*)  alloc((size_t)NB * NJ * 4);
    int*   rank   = (int*)  alloc((size_t)NB * NJ * 4);
    int*   hist   = (int*)  alloc((size_t)NB * NJ * 4);
    int*   sidx   = (int*)  alloc((size_t)NB * NJ * 4);
    int*   undo   = (int*)  alloc((size_t)NB * NJ * 4);
    float* bs     = (float*)alloc((size_t)NB * NJ * 4);
    unsigned short* Osort = (unsigned short*)alloc((size_t)NB * NJ * CHN * 2);
    unsigned short* wmT_hi = (unsigned short*)alloc((size_t)9 * 64 * CHN * 2);
    unsigned short* wmT_lo = (unsigned short*)alloc((size_t)9 * 64 * CHN * 2);
    // in_lo (18.9 MB) aliases the head of Osort (75.5 MB): in_lo is written by
    // cvt_in_hilo_k and last read by conv_match_mfma_k, both strictly before
    // attn_mfma_k writes Osort on the same stream.
    unsigned short* in_lo = Osort;

    // input hi/lo split (hi also feeds the value-path conv)
    cvt_in_hilo_k<<<dim3(4608), 256, 0, stream>>>(input, in_bf, in_lo);
    // match path (split-bf16 MFMA — feeds hashing at ~fp32 precision)
    cvt_wm_hilo_k<<<dim3(8, 2, 9), 256, 0, stream>>>(w_match, wmT_hi, wmT_lo);
    conv_match_mfma_k<<<dim3(144, 1, NB), 256, 0, stream>>>(in_bf, in_lo, wmT_hi, wmT_lo, b_match, xm);
    transpose_k<<<dim3(288, 2, NB), 256, 0, stream>>>(xm, xmT, xmT_bf, CC, LL);
    // value path (bf16 MFMA)
    cvt_wT_k<<<dim3(8, 8, 9), 256, 0, stream>>>(w_asm, wT_bf);
    conv_mfma_k<<<dim3(72, 2, NB), 256, 0, stream>>>(in_bf, wT_bf, b_asm, ya_bf);
    transpose_bf_k<<<dim3(144, 4, NB), 256, 0, stream>>>(ya_bf, yaT);
    // hashing + sort
    hash_k<<<dim3(144, NHASH), 256, 0, stream>>>(xmT, rot, codes, ssq);
    sort_hist_k<<<dim3(144, NB), 256, 0, stream>>>(codes, hist, rank);
    sort_scan_k<<<dim3(NB), 256, 0, stream>>>(hist);
    sort_scatter_k<<<dim3(144, NB), 256, 0, stream>>>(codes, rank, hist, sidx, undo);
    // attention + combine
    attn_mfma_k<<<dim3(NCHUNK, NHASH, NB), 1024, 0, stream>>>(xmT_bf, yaT, ssq, sidx, Osort, bs);
    combfin_k<<<dim3(288, NB), 256, 0, stream>>>(Osort, bs, undo, input, out);
}

// Round 11
// 433.830 us; speedup vs baseline: 1.3153x; 1.0496x over previous
//
#include <hip/hip_runtime.h>
#include <cstdint>
#include <cstddef>

#define NB 4
#define HH 96
#define WW 96
#define CHN 256
#define CC 64
#define LL 9216
#define NHASH 4
#define HBK 64
#define CHK 144
#define NCHUNK 64
#define NJ 36864   // NHASH * LL

typedef __attribute__((ext_vector_type(8))) short bf16x8;
typedef __attribute__((ext_vector_type(8))) unsigned short u16x8;
typedef __attribute__((ext_vector_type(4))) float f32x4;

__device__ __forceinline__ unsigned short f2b(float f) {
    unsigned int x = __float_as_uint(f);
    x += 0x7FFFu + ((x >> 16) & 1u);
    return (unsigned short)(x >> 16);
}
__device__ __forceinline__ float b2f(unsigned short u) {
    return __uint_as_float(((unsigned int)u) << 16);
}

// ---------------------------------------------------------------- input fp32 -> bf16 hi + bf16 lo residual
__global__ __launch_bounds__(256) void cvt_in_hilo_k(const float* __restrict__ in,
                                                     unsigned short* __restrict__ hi,
                                                     unsigned short* __restrict__ lo)
{
    size_t g = ((size_t)blockIdx.x * 256 + threadIdx.x) * 8;
    float4 v0 = *(const float4*)(in + g);
    float4 v1 = *(const float4*)(in + g + 4);
    float xs[8] = {v0.x, v0.y, v0.z, v0.w, v1.x, v1.y, v1.z, v1.w};
    u16x8 h, l;
#pragma unroll
    for (int i = 0; i < 8; i++) {
        unsigned short hv = f2b(xs[i]);
        h[i] = hv;
        l[i] = f2b(xs[i] - b2f(hv));
    }
    *(u16x8*)(hi + g) = h;
    *(u16x8*)(lo + g) = l;
}

// ---------------------------------------------------------------- w_match [tap][ci][64] fp32 -> wmT [tap][co=64][ci=256] bf16 hi/lo
__global__ __launch_bounds__(256) void cvt_wm_hilo_k(const float* __restrict__ w,
                                                     unsigned short* __restrict__ hiT,
                                                     unsigned short* __restrict__ loT)
{
    __shared__ float tl[32][33];
    const int tap = blockIdx.z;
    const int c0 = blockIdx.x * 32;   // ci
    const int o0 = blockIdx.y * 32;   // co
    const int tx = threadIdx.x & 31, ty0 = threadIdx.x >> 5;
#pragma unroll
    for (int i = 0; i < 32; i += 8)
        tl[ty0 + i][tx] = w[((size_t)tap * 256 + c0 + ty0 + i) * 64 + o0 + tx];
    __syncthreads();
#pragma unroll
    for (int i = 0; i < 32; i += 8) {
        float v = tl[tx][ty0 + i];
        unsigned short h = f2b(v);
        size_t o = ((size_t)tap * 64 + o0 + ty0 + i) * 256 + c0 + tx;
        hiT[o] = h;
        loT[o] = f2b(v - b2f(h));
    }
}

// ---------------------------------------------------------------- MFMA conv 3x3 (match path, split-bf16 ~fp32 precision)
// v5: ci-64 steps + T14 register prefetch in a COMPILE-SAFE encoding. Round-6's
// version (flat 72-iter loop + twice-inlined load lambda) killed the container —
// attributed to unroll/inline explosion. Here: flat 36-iter loop with
// #pragma unroll 1 (body emitted once), inline address math (no lambda), and
// register reuse (stores kill the staging regs; next-iteration loads refill the
// same regs). Loads issue between the two barriers -> ~500cy latency spans
// barrier + MFMA instead of sitting exposed.
#define ASTR2 72
__global__ __launch_bounds__(256, 2) void conv_match_mfma_k(
    const unsigned short* __restrict__ in_hi, const unsigned short* __restrict__ in_lo,
    const unsigned short* __restrict__ wmT_hi, const unsigned short* __restrict__ wmT_lo,
    const float* __restrict__ bias, float* __restrict__ xm)
{
    __shared__ short Ah[64 * ASTR2], Al[64 * ASTR2];
    __shared__ short Bh[64 * ASTR2], Bl[64 * ASTR2];
    const int n = blockIdx.z, p0 = blockIdx.x * 64;
    const int tid = threadIdx.x;
    const int w = tid >> 6;
    const int lane = tid & 63, lm = lane & 15, lq = lane >> 4;
    const int r = tid >> 2, q8 = (tid & 3) * 8;      // staging: row 0..63, 8-short quarter per half
    const int p = p0 + r, py = p / WW, px = p % WW;
    const unsigned short* hiN = in_hi + (size_t)n * LL * CHN;
    const unsigned short* loN = in_lo + (size_t)n * LL * CHN;

    f32x4 acc[4];
#pragma unroll
    for (int b = 0; b < 4; b++) acc[b] = (f32x4){0.f, 0.f, 0.f, 0.f};

    // preload it=0 (tap 0 = ky0 kx0, ci0 = 0)
    u16x8 avh0 = (u16x8){0,0,0,0,0,0,0,0}, avh1 = (u16x8){0,0,0,0,0,0,0,0};
    u16x8 avl0 = (u16x8){0,0,0,0,0,0,0,0}, avl1 = (u16x8){0,0,0,0,0,0,0,0};
    u16x8 bvh0, bvh1, bvl0, bvl1;
    {
        int sy = py - 1, sx = px - 1;
        if (((unsigned)sy < HH) && ((unsigned)sx < WW)) {
            size_t ao = (size_t)(sy * WW + sx) * CHN + q8;
            avh0 = *(const u16x8*)(hiN + ao);
            avh1 = *(const u16x8*)(hiN + ao + 32);
            avl0 = *(const u16x8*)(loN + ao);
            avl1 = *(const u16x8*)(loN + ao + 32);
        }
        size_t bo = (size_t)r * 256 + q8;
        bvh0 = *(const u16x8*)(wmT_hi + bo);
        bvh1 = *(const u16x8*)(wmT_hi + bo + 32);
        bvl0 = *(const u16x8*)(wmT_lo + bo);
        bvl1 = *(const u16x8*)(wmT_lo + bo + 32);
    }

#pragma unroll 1
    for (int it = 0; it < 36; it++) {
        __syncthreads();   // prior MFMA reads of LDS done
        *(u16x8*)&Ah[r * ASTR2 + q8]      = avh0;
        *(u16x8*)&Ah[r * ASTR2 + q8 + 32] = avh1;
        *(u16x8*)&Al[r * ASTR2 + q8]      = avl0;
        *(u16x8*)&Al[r * ASTR2 + q8 + 32] = avl1;
        *(u16x8*)&Bh[r * ASTR2 + q8]      = bvh0;
        *(u16x8*)&Bh[r * ASTR2 + q8 + 32] = bvh1;
        *(u16x8*)&Bl[r * ASTR2 + q8]      = bvl0;
        *(u16x8*)&Bl[r * ASTR2 + q8 + 32] = bvl1;
        // prefetch next step into the (now dead) staging regs
        if (it < 35) {
            int nit = it + 1;
            int ntap = nit >> 2, nci = (nit & 3) << 6;
            int ky = ntap / 3, kx = ntap - ky * 3;
            int sy = py + ky - 1, sx = px + kx - 1;
            avh0 = (u16x8){0,0,0,0,0,0,0,0}; avh1 = (u16x8){0,0,0,0,0,0,0,0};
            avl0 = (u16x8){0,0,0,0,0,0,0,0}; avl1 = (u16x8){0,0,0,0,0,0,0,0};
            if (((unsigned)sy < HH) && ((unsigned)sx < WW)) {
                size_t ao = (size_t)(sy * WW + sx) * CHN + q8 + nci;
                avh0 = *(const u16x8*)(hiN + ao);
                avh1 = *(const u16x8*)(hiN + ao + 32);
                avl0 = *(const u16x8*)(loN + ao);
                avl1 = *(const u16x8*)(loN + ao + 32);
            }
            size_t bo = ((size_t)ntap * 64 + r) * 256 + q8 + nci;
            bvh0 = *(const u16x8*)(wmT_hi + bo);
            bvh1 = *(const u16x8*)(wmT_hi + bo + 32);
            bvl0 = *(const u16x8*)(wmT_lo + bo);
            bvl1 = *(const u16x8*)(wmT_lo + bo + 32);
        }
        __syncthreads();   // tiles ready
#pragma unroll
        for (int cs = 0; cs < 2; cs++) {
            bf16x8 afh = *(const bf16x8*)&Ah[(w * 16 + lm) * ASTR2 + cs * 32 + lq * 8];
            bf16x8 afl = *(const bf16x8*)&Al[(w * 16 + lm) * ASTR2 + cs * 32 + lq * 8];
#pragma unroll
            for (int nt = 0; nt < 4; nt++) {
                bf16x8 bfh = *(const bf16x8*)&Bh[(nt * 16 + lm) * ASTR2 + cs * 32 + lq * 8];
                bf16x8 bfl = *(const bf16x8*)&Bl[(nt * 16 + lm) * ASTR2 + cs * 32 + lq * 8];
                acc[nt] = __builtin_amdgcn_mfma_f32_16x16x32_bf16(afh, bfh, acc[nt], 0, 0, 0);
                acc[nt] = __builtin_amdgcn_mfma_f32_16x16x32_bf16(afh, bfl, acc[nt], 0, 0, 0);
                acc[nt] = __builtin_amdgcn_mfma_f32_16x16x32_bf16(afl, bfh, acc[nt], 0, 0, 0);
            }
        }
    }
    float bvv[4];
#pragma unroll
    for (int nt = 0; nt < 4; nt++) bvv[nt] = bias[nt * 16 + lm];
    float* outN = xm + (size_t)n * LL * 64;
#pragma unroll
    for (int r4 = 0; r4 < 4; r4++) {
        int row = p0 + w * 16 + lq * 4 + r4;
        float* od = outN + (size_t)row * 64;
#pragma unroll
        for (int nt = 0; nt < 4; nt++)
            od[nt * 16 + lm] = acc[nt][r4] + bvv[nt];
    }
}

// ---------------------------------------------------------------- fp32 transpose (match embedding) + bf16 copy
__global__ __launch_bounds__(256) void transpose_k(const float* __restrict__ in, float* __restrict__ out,
                                                   unsigned short* __restrict__ out_bf, int R, int Cc)
{
    __shared__ float tl[32][33];
    const int n = blockIdx.z;
    const size_t base = (size_t)n * R * Cc;
    int c0 = blockIdx.x * 32, r0 = blockIdx.y * 32;
    int tx = threadIdx.x & 31, ty0 = threadIdx.x >> 5;
#pragma unroll
    for (int i = 0; i < 32; i += 8)
        tl[ty0 + i][tx] = in[base + (size_t)(r0 + ty0 + i) * Cc + c0 + tx];
    __syncthreads();
#pragma unroll
    for (int i = 0; i < 32; i += 8) {
        float v = tl[tx][ty0 + i];
        size_t o = base + (size_t)(c0 + ty0 + i) * R + r0 + tx;
        out[o] = v;
        out_bf[o] = f2b(v);
    }
}

// ---------------------------------------------------------------- w_asm [tap][ci][co] fp32 -> wT [tap][co][ci] bf16
__global__ __launch_bounds__(256) void cvt_wT_k(const float* __restrict__ w, unsigned short* __restrict__ wT)
{
    __shared__ float tl[32][33];
    const int tap = blockIdx.z;
    const int c0 = blockIdx.x * 32;
    const int o0 = blockIdx.y * 32;
    const int tx = threadIdx.x & 31, ty0 = threadIdx.x >> 5;
#pragma unroll
    for (int i = 0; i < 32; i += 8)
        tl[ty0 + i][tx] = w[((size_t)tap * 256 + c0 + ty0 + i) * 256 + o0 + tx];
    __syncthreads();
#pragma unroll
    for (int i = 0; i < 32; i += 8)
        wT[((size_t)tap * 256 + o0 + ty0 + i) * 256 + c0 + tx] = f2b(tl[tx][ty0 + i]);
}

// ---------------------------------------------------------------- MFMA conv 3x3 (value path, bf16)
// v4: ci-64 steps + compile-safe T14 prefetch (same encoding as conv_match v5).
__global__ __launch_bounds__(256) void conv_mfma_k(
    const unsigned short* __restrict__ in_bf, const unsigned short* __restrict__ wT,
    const float* __restrict__ bias, unsigned short* __restrict__ ya_bf)
{
    __shared__ short As[128 * ASTR2];
    __shared__ short Bs[128 * ASTR2];
    const int n = blockIdx.z, p0 = blockIdx.x * 128, co0 = blockIdx.y * 128;
    const int tid = threadIdx.x;
    const int w = tid >> 6, wr = w >> 1, wc = w & 1;
    const int lane = tid & 63, lm = lane & 15, lq = lane >> 4;
    const int r = tid >> 1, hf = tid & 1;            // staging: row 0..127, 32-short half
    const int p = p0 + r, py = p / WW, px = p % WW;
    const unsigned short* inN = in_bf + (size_t)n * LL * CHN;

    f32x4 acc[4][4];
#pragma unroll
    for (int a = 0; a < 4; a++)
#pragma unroll
        for (int b = 0; b < 4; b++) acc[a][b] = (f32x4){0.f, 0.f, 0.f, 0.f};

    // preload it=0 (tap 0, ci0 = 0)
    u16x8 av0 = (u16x8){0,0,0,0,0,0,0,0}, av1 = (u16x8){0,0,0,0,0,0,0,0};
    u16x8 av2 = (u16x8){0,0,0,0,0,0,0,0}, av3 = (u16x8){0,0,0,0,0,0,0,0};
    u16x8 bv0, bv1, bv2, bv3;
    {
        int sy = py - 1, sx = px - 1;
        if (((unsigned)sy < HH) && ((unsigned)sx < WW)) {
            const unsigned short* asrc = inN + (size_t)(sy * WW + sx) * CHN + hf * 32;
            av0 = *(const u16x8*)(asrc);
            av1 = *(const u16x8*)(asrc + 8);
            av2 = *(const u16x8*)(asrc + 16);
            av3 = *(const u16x8*)(asrc + 24);
        }
        const unsigned short* bsrc = wT + ((size_t)co0 + r) * 256 + hf * 32;
        bv0 = *(const u16x8*)(bsrc);
        bv1 = *(const u16x8*)(bsrc + 8);
        bv2 = *(const u16x8*)(bsrc + 16);
        bv3 = *(const u16x8*)(bsrc + 24);
    }

#pragma unroll 1
    for (int it = 0; it < 36; it++) {
        __syncthreads();
        *(u16x8*)&As[r * ASTR2 + hf * 32]      = av0;
        *(u16x8*)&As[r * ASTR2 + hf * 32 + 8]  = av1;
        *(u16x8*)&As[r * ASTR2 + hf * 32 + 16] = av2;
        *(u16x8*)&As[r * ASTR2 + hf * 32 + 24] = av3;
        *(u16x8*)&Bs[r * ASTR2 + hf * 32]      = bv0;
        *(u16x8*)&Bs[r * ASTR2 + hf * 32 + 8]  = bv1;
        *(u16x8*)&Bs[r * ASTR2 + hf * 32 + 16] = bv2;
        *(u16x8*)&Bs[r * ASTR2 + hf * 32 + 24] = bv3;
        if (it < 35) {
            int nit = it + 1;
            int ntap = nit >> 2, nci = (nit & 3) << 6;
            int ky = ntap / 3, kx = ntap - ky * 3;
            int sy = py + ky - 1, sx = px + kx - 1;
            av0 = (u16x8){0,0,0,0,0,0,0,0}; av1 = (u16x8){0,0,0,0,0,0,0,0};
            av2 = (u16x8){0,0,0,0,0,0,0,0}; av3 = (u16x8){0,0,0,0,0,0,0,0};
            if (((unsigned)sy < HH) && ((unsigned)sx < WW)) {
                const unsigned short* asrc = inN + (size_t)(sy * WW + sx) * CHN + hf * 32 + nci;
                av0 = *(const u16x8*)(asrc);
                av1 = *(const u16x8*)(asrc + 8);
                av2 = *(const u16x8*)(asrc + 16);
                av3 = *(const u16x8*)(asrc + 24);
            }
            const unsigned short* bsrc = wT + ((size_t)ntap * 256 + co0 + r) * 256 + hf * 32 + nci;
            bv0 = *(const u16x8*)(bsrc);
            bv1 = *(const u16x8*)(bsrc + 8);
            bv2 = *(const u16x8*)(bsrc + 16);
            bv3 = *(const u16x8*)(bsrc + 24);
        }
        __syncthreads();
#pragma unroll
        for (int cs = 0; cs < 2; cs++) {
            bf16x8 af[4], bf[4];
#pragma unroll
            for (int mt = 0; mt < 4; mt++)
                af[mt] = *(const bf16x8*)&As[(wr * 64 + mt * 16 + lm) * ASTR2 + cs * 32 + lq * 8];
#pragma unroll
            for (int nt = 0; nt < 4; nt++)
                bf[nt] = *(const bf16x8*)&Bs[(wc * 64 + nt * 16 + lm) * ASTR2 + cs * 32 + lq * 8];
#pragma unroll
            for (int mt = 0; mt < 4; mt++)
#pragma unroll
                for (int nt = 0; nt < 4; nt++)
                    acc[mt][nt] = __builtin_amdgcn_mfma_f32_16x16x32_bf16(af[mt], bf[nt], acc[mt][nt], 0, 0, 0);
        }
    }
    float bv[4];
#pragma unroll
    for (int nt = 0; nt < 4; nt++) bv[nt] = bias[co0 + wc * 64 + nt * 16 + lm];
#pragma unroll
    for (int mt = 0; mt < 4; mt++) {
#pragma unroll
        for (int r4 = 0; r4 < 4; r4++) {
            int row = p0 + wr * 64 + mt * 16 + lq * 4 + r4;
            unsigned short* od = ya_bf + ((size_t)n * LL + row) * CHN + co0 + wc * 64;
#pragma unroll
            for (int nt = 0; nt < 4; nt++)
                od[nt * 16 + lm] = f2b(acc[mt][nt][r4] + bv[nt]);
        }
    }
}

// ---------------------------------------------------------------- bf16 transpose: ya_bf (viewed [256][9216]) -> yaT [9216][256]
__global__ __launch_bounds__(256) void transpose_bf_k(const unsigned short* __restrict__ in,
                                                      unsigned short* __restrict__ out)
{
    __shared__ unsigned short tl[64][65];
    const int n = blockIdx.z;
    const size_t base = (size_t)n * LL * CHN;
    const int t0 = blockIdx.x * 64, e0 = blockIdx.y * 64;
    const int tx = threadIdx.x & 63, ty0 = threadIdx.x >> 6;
#pragma unroll
    for (int i = 0; i < 16; i++) {
        int row = ty0 + i * 4;
        tl[row][tx] = in[base + (size_t)(e0 + row) * LL + t0 + tx];
    }
    __syncthreads();
#pragma unroll
    for (int i = 0; i < 16; i++) {
        int row = ty0 + i * 4;
        out[base + (size_t)(t0 + row) * CHN + e0 + tx] = tl[tx][row];
    }
}

// ---------------------------------------------------------------- hashing: codes + squared norms (fp32!)
__global__ __launch_bounds__(256) void hash_k(const float* __restrict__ xmT, const float* __restrict__ rot,
                                              int* __restrict__ codes, float* __restrict__ ssq)
{
    __shared__ float rs[32 * 68];   // [i][f], stride 68, this block's hash only
    const int h = blockIdx.y;
    for (int e = threadIdx.x; e < 2048; e += 256) {
        int hi = e >> 6, f = e & 63;
        rs[hi * 68 + f] = rot[f * 128 + h * 32 + hi];
    }
    __syncthreads();
    int g = blockIdx.x * 256 + threadIdx.x;
    int n = g / LL, t = g % LL;
    float4 x4[16];
    const float* src = xmT + (size_t)g * CC;
#pragma unroll
    for (int f4 = 0; f4 < 16; f4++) x4[f4] = *(const float4*)(src + f4 * 4);
    if (h == 0) {
        float ss = 0.f;
#pragma unroll
        for (int f4 = 0; f4 < 16; f4++)
            ss += x4[f4].x * x4[f4].x + x4[f4].y * x4[f4].y + x4[f4].z * x4[f4].z + x4[f4].w * x4[f4].w;
        ssq[g] = ss;
    }
    float bp = -1e30f, bn = -1e30f;
    int ip = 0, inn = 0;
    for (int i = 0; i < 32; i++) {
        const float* rr = &rs[i * 68];
        float d0 = 0.f, d1 = 0.f, d2 = 0.f, d3 = 0.f;
#pragma unroll
        for (int f4 = 0; f4 < 16; f4++) {
            float4 r4 = *(const float4*)(rr + f4 * 4);
            d0 = fmaf(x4[f4].x, r4.x, d0);
            d1 = fmaf(x4[f4].y, r4.y, d1);
            d2 = fmaf(x4[f4].z, r4.z, d2);
            d3 = fmaf(x4[f4].w, r4.w, d3);
        }
        float d = (d0 + d1) + (d2 + d3);
        if (d > bp) { bp = d; ip = i; }
        if (-d > bn) { bn = -d; inn = i; }
    }
    int code = (bp >= bn) ? ip : (32 + inn);
    codes[(size_t)n * NJ + h * LL + t] = code + h * HBK;
}

// ---------------------------------------------------------------- stable counting sort (256 buckets)
__global__ __launch_bounds__(256) void sort_hist_k(const int* __restrict__ codes, int* __restrict__ hist,
                                                   int* __restrict__ rank)
{
    __shared__ int lhw[4][256];
    const int n = blockIdx.y, seg = blockIdx.x, tid = threadIdx.x;
    const int w = tid >> 6, lane = tid & 63;
    int j = seg * 256 + tid;
    int c = codes[(size_t)n * NJ + j];
    for (int e = tid; e < 1024; e += 256) ((int*)lhw)[e] = 0;
    __syncthreads();
    unsigned long long eq = ~0ull;
#pragma unroll
    for (int b = 0; b < 8; b++) {
        unsigned long long m = __ballot((c >> b) & 1);
        eq &= ((c >> b) & 1) ? m : ~m;
    }
    int rw = __popcll(eq & ((1ull << lane) - 1ull));   // rank within wave (tid order)
    int cntw = __popcll(eq);                           // class count in this wave
    if (rw == 0) lhw[w][c] = cntw;                     // unique (w,c) writer
    __syncthreads();
    int base = 0;
    if (w > 0) base += lhw[0][c];
    if (w > 1) base += lhw[1][c];
    if (w > 2) base += lhw[2][c];
    rank[(size_t)n * NJ + j] = base + rw;
    hist[(size_t)n * NJ + tid * 144 + seg] = lhw[0][tid] + lhw[1][tid] + lhw[2][tid] + lhw[3][tid];
}

__global__ __launch_bounds__(256) void sort_scan_k(int* __restrict__ hist)
{
    const int n = blockIdx.x;
    const int key = threadIdx.x;
    int* hn = hist + (size_t)n * NJ;
    int sum = 0;
    for (int s = 0; s < 144; s++) sum += hn[key * 144 + s];
    __shared__ int sc[256];
    sc[key] = sum;
    __syncthreads();
    for (int off = 1; off < 256; off <<= 1) {
        int v = (key >= off) ? sc[key - off] : 0;
        __syncthreads();
        sc[key] += v;
        __syncthreads();
    }
    int run = sc[key] - sum;   // exclusive prefix
    for (int s = 0; s < 144; s++) { int v = hn[key * 144 + s]; hn[key * 144 + s] = run; run += v; }
}

__global__ __launch_bounds__(256) void sort_scatter_k(const int* __restrict__ codes, const int* __restrict__ rank,
                                                      const int* __restrict__ hist, int* __restrict__ sidx,
                                                      int* __restrict__ undo)
{
    const int n = blockIdx.y, seg = blockIdx.x, tid = threadIdx.x;
    int j = seg * 256 + tid;
    int c = codes[(size_t)n * NJ + j];
    int dest = hist[(size_t)n * NJ + c * 144 + seg] + rank[(size_t)n * NJ + j];
    sidx[(size_t)n * NJ + dest] = j;
    undo[(size_t)n * NJ + j] = dest;
}

// ---------------------------------------------------------------- MFMA attention v5 (verified 124us — unchanged)
#define QSTR 72     // Q/K row stride in shorts
#define PSTR 164    // P row stride in shorts (conflict-free write quadrants)
__global__ __launch_bounds__(1024, 4) __attribute__((amdgpu_waves_per_eu(4, 4))) void attn_mfma_k(
    const unsigned short* __restrict__ xmT_bf, const unsigned short* __restrict__ yaT,
    const float* __restrict__ ssq, const int* __restrict__ sidx,
    unsigned short* __restrict__ Osort, float* __restrict__ bs)
{
    __shared__ short Qs[144 * QSTR];
    __shared__ short Ks[144 * QSTR];
    __shared__ short Ps[144 * PSTR];
    __shared__ int   tIdx[432];
    __shared__ int   voff[432];
    __shared__ float nfs[432];
    __shared__ float qlen[432];
    __shared__ float lsum[144];
    __shared__ float linv[144];

    const int k = blockIdx.x, h = blockIdx.y, n = blockIdx.z;
    const int tid = threadIdx.x;
    const int w = tid >> 6, lane = tid & 63;
    const int lm = lane & 15, lq = lane >> 4;
    const size_t sbase = (size_t)n * NJ + (size_t)h * LL;

    if (tid < 432) {
        int cc = tid / CHK, rr = tid - cc * CHK;
        int c = (cc == 0) ? k : (cc == 1 ? (k + NCHUNK - 1) & (NCHUNK - 1) : (k + 1) & (NCHUNK - 1));
        int j = sidx[sbase + c * CHK + rr];
        int t = j % LL;
        tIdx[tid] = t;
        voff[tid] = t * (CHN * 2);
        float m = fmaxf(ssq[(size_t)n * LL + t], 5e-5f);
        float nf = rsqrtf(m);
        nfs[tid] = nf;
        qlen[tid] = m * nf;   // sqrt(m) = |q| clamped
    }
    __syncthreads();   // tIdx/voff/nfs/qlen ready

    // stage Q rows (raw bf16)
    const int sr = tid >> 3, sj = (tid & 7) * 8;
    const int sr2 = (tid + 1024) >> 3, sj2 = (tid & 7) * 8;
    {
        u16x8 v = *(const u16x8*)(xmT_bf + ((size_t)n * LL + tIdx[sr]) * CC + sj);
        *(u16x8*)&Qs[sr * QSTR + sj] = v;
        if (tid < 128) {
            u16x8 v2 = *(const u16x8*)(xmT_bf + ((size_t)n * LL + tIdx[sr2]) * CC + sj2);
            *(u16x8*)&Qs[sr2 * QSTR + sj2] = v2;
        }
    }
    // zero P pad columns 144..159 once (P writes later touch cols 0..143 only)
    for (int e = tid; e < 2304; e += 1024) {
        int r = e >> 4, c = 144 + (e & 15);
        Ps[r * PSTR + c] = 0;
    }
    // T14: issue chunk-1 K loads into registers now (consumed at top of chunk 1)
    u16x8 kreg0, kreg1;
    kreg0 = *(const u16x8*)(xmT_bf + ((size_t)n * LL + tIdx[CHK + sr]) * CC + sj);
    if (tid < 128)
        kreg1 = *(const u16x8*)(xmT_bf + ((size_t)n * LL + tIdx[CHK + sr2]) * CC + sj2);

    const char* vbase = (const char*)(yaT + (size_t)n * LL * CHN + w * 16 + lm);
    f32x4 accO[9];
#pragma unroll
    for (int mt = 0; mt < 9; mt++) accO[mt] = (f32x4){0.f, 0.f, 0.f, 0.f};
    f32x4 accL = (f32x4){0.f, 0.f, 0.f, 0.f};
    bf16x8 onesF, onesL;
#pragma unroll
    for (int i = 0; i < 8; i++) {
        onesF[i] = (short)0x3F80;
        onesL[i] = (lq < 2) ? (short)0x3F80 : (short)0;   // mask pad keys 144..159 (k-step 4, lq>=2)
    }

    for (int cc = 0; cc < 3; cc++) {
        const int c144 = cc * CHK;
        if (cc > 0) {
            *(u16x8*)&Ks[sr * QSTR + sj] = kreg0;
            if (tid < 128) *(u16x8*)&Ks[sr2 * QSTR + sj2] = kreg1;
        }
        if (cc < 2) {
            kreg0 = *(const u16x8*)(xmT_bf + ((size_t)n * LL + tIdx[(cc + 1) * CHK + sr]) * CC + sj);
            if (tid < 128)
                kreg1 = *(const u16x8*)(xmT_bf + ((size_t)n * LL + tIdx[(cc + 1) * CHK + sr2]) * CC + sj2);
        }
        // V B-frag gathers from global — issued early, consumed after QK (latency hidden)
        bf16x8 vfrag[5];
#pragma unroll
        for (int ks = 0; ks < 5; ks++) {
            int kb = ks * 32 + lq * 8;
            if (kb < 144) {
                int4 o0 = *(const int4*)&voff[c144 + kb];
                int4 o1 = *(const int4*)&voff[c144 + kb + 4];
                vfrag[ks][0] = (short)*(const unsigned short*)(vbase + o0.x);
                vfrag[ks][1] = (short)*(const unsigned short*)(vbase + o0.y);
                vfrag[ks][2] = (short)*(const unsigned short*)(vbase + o0.z);
                vfrag[ks][3] = (short)*(const unsigned short*)(vbase + o0.w);
                vfrag[ks][4] = (short)*(const unsigned short*)(vbase + o1.x);
                vfrag[ks][5] = (short)*(const unsigned short*)(vbase + o1.y);
                vfrag[ks][6] = (short)*(const unsigned short*)(vbase + o1.z);
                vfrag[ks][7] = (short)*(const unsigned short*)(vbase + o1.w);
            } else {
                vfrag[ks] = (bf16x8){0, 0, 0, 0, 0, 0, 0, 0};
            }
        }
        __syncthreads();

        // QK (B^T GEMM) + exp; raw scores post-scaled by key norm; P written straight to LDS
        const short* Bsrc = (cc == 0) ? Qs : Ks;
        for (int tt = w; tt < 81; tt += 16) {
            int mt = tt / 9, nt = tt - mt * 9;
            f32x4 c = {0.f, 0.f, 0.f, 0.f};
#pragma unroll
            for (int ks = 0; ks < 2; ks++) {
                bf16x8 a = *(const bf16x8*)&Qs[(mt * 16 + lm) * QSTR + ks * 32 + lq * 8];
                bf16x8 b = *(const bf16x8*)&Bsrc[(nt * 16 + lm) * QSTR + ks * 32 + lq * 8];
                c = __builtin_amdgcn_mfma_f32_16x16x32_bf16(a, b, c, 0, 0, 0);
            }
            float nfk = nfs[c144 + nt * 16 + lm];
#pragma unroll
            for (int r = 0; r < 4; r++) {
                int mrow = mt * 16 + lq * 4 + r;
                float p = __expf(fmaf(c[r], nfk, -qlen[mrow]));
                Ps[mrow * PSTR + nt * 16 + lm] = (short)f2b(p);
            }
        }
        __syncthreads();   // Ps ready (pad cols are permanent zeros)

        // lsum via ones-MFMA (waves 0..8, mt = w)
        if (w < 9) {
#pragma unroll
            for (int ks = 0; ks < 5; ks++) {
                bf16x8 a = *(const bf16x8*)&Ps[(w * 16 + lm) * PSTR + ks * 32 + lq * 8];
                accL = __builtin_amdgcn_mfma_f32_16x16x32_bf16(a, (ks == 4) ? onesL : onesF, accL, 0, 0, 0);
            }
        }
        // PV: 9 m-tiles, V frags in registers
#pragma unroll
        for (int mt = 0; mt < 9; mt++) {
            f32x4 c = accO[mt];
#pragma unroll
            for (int ks = 0; ks < 5; ks++) {
                bf16x8 a = *(const bf16x8*)&Ps[(mt * 16 + lm) * PSTR + ks * 32 + lq * 8];
                c = __builtin_amdgcn_mfma_f32_16x16x32_bf16(a, vfrag[ks], c, 0, 0, 0);
            }
            accO[mt] = c;
        }
    }

    if (w < 9 && lm == 0) {
#pragma unroll
        for (int r = 0; r < 4; r++) lsum[w * 16 + lq * 4 + r] = accL[r];
    }
    __syncthreads();
    if (tid < 144) {
        float l = lsum[tid];
        linv[tid] = 1.0f / l;
        bs[sbase + tIdx[tid]] = qlen[tid] + __logf(l);
    }
    __syncthreads();

#pragma unroll
    for (int mt = 0; mt < 9; mt++) {
        f32x4 c = accO[mt];
#pragma unroll
        for (int r = 0; r < 4; r++) {
            int mrow = mt * 16 + lq * 4 + r;
            Osort[(sbase + (size_t)k * CHK + mrow) * CHN + w * 16 + lm] = f2b(c[r] * linv[mrow]);
        }
    }
}

// ---------------------------------------------------------------- combine (4 hashes, inline softmax) + transpose + residual
__global__ __launch_bounds__(256) void combfin_k(
    const unsigned short* __restrict__ Osort, const float* __restrict__ bs,
    const int* __restrict__ undo, const float* __restrict__ inp, float* __restrict__ out)
{
    __shared__ float ac[32][260];
    __shared__ int   uS[4][32];
    __shared__ float pS[4][32];
    const int n = blockIdx.y;
    const int t0 = blockIdx.x * 32;
    const int tid = threadIdx.x;
    if (tid < 128) {
        int hh = tid >> 5, tt = tid & 31;
        size_t idx = (size_t)n * NJ + (size_t)hh * LL + t0 + tt;
        uS[hh][tt] = undo[idx];
        pS[hh][tt] = bs[idx];
    }
    __syncthreads();
    if (tid < 32) {
        float b0 = pS[0][tid], b1 = pS[1][tid], b2 = pS[2][tid], b3 = pS[3][tid];
        float mx = fmaxf(fmaxf(b0, b1), fmaxf(b2, b3));
        float e0 = __expf(b0 - mx), e1 = __expf(b1 - mx), e2 = __expf(b2 - mx), e3 = __expf(b3 - mx);
        float inv = 1.f / (e0 + e1 + e2 + e3);
        pS[0][tid] = e0 * inv; pS[1][tid] = e1 * inv; pS[2][tid] = e2 * inv; pS[3][tid] = e3 * inv;
    }
    __syncthreads();
    const int g = tid & 63, tq = tid >> 6;
    for (int tt8 = 0; tt8 < 8; tt8++) {
        int t = tq * 8 + tt8;
        float a0 = 0.f, a1 = 0.f, a2 = 0.f, a3 = 0.f;
#pragma unroll
        for (int hh = 0; hh < 4; hh++) {
            int row = uS[hh][t];
            float p = pS[hh][t];
            ushort4 u = *(const ushort4*)&Osort[((size_t)n * NJ + row) * CHN + g * 4];
            a0 = fmaf(p, b2f(u.x), a0);
            a1 = fmaf(p, b2f(u.y), a1);
            a2 = fmaf(p, b2f(u.z), a2);
            a3 = fmaf(p, b2f(u.w), a3);
        }
        *(float4*)&ac[t][g * 4] = make_float4(a0, a1, a2, a3);
    }
    __syncthreads();
    const int tp = tid & 31, er = tid >> 5;
    const float* inN = inp + (size_t)n * LL * CHN;
    float* outN = out + (size_t)n * LL * CHN;
    for (int it = 0; it < 32; it++) {
        int e = er + it * 8;
        size_t o = (size_t)e * LL + t0 + tp;
        outN[o] = ac[tp][e] * 0.1f + inN[o];
    }
}

// ---------------------------------------------------------------- launch
extern "C" void kernel_launch(void* const* d_in, const int* in_sizes, int n_in,
                              void* d_out, int out_size, void* d_ws, size_t ws_size,
                              hipStream_t stream)
{
    (void)in_sizes; (void)n_in; (void)out_size; (void)ws_size;
    const float* input   = (const float*)d_in[0];
    const float* w_match = (const float*)d_in[1];
    const float* b_match = (const float*)d_in[2];
    const float* w_asm   = (const float*)d_in[3];
    const float* b_asm   = (const float*)d_in[4];
    const float* rot     = (const float*)d_in[5];
    float* out = (float*)d_out;

    char* ws = (char*)d_ws;
    size_t off = 0;
    auto alloc = [&](size_t bytes) -> void* {
        void* p = ws + off;
        off += (bytes + 255) & ~(size_t)255;
        return p;
    };
    unsigned short* in_bf  = (unsigned short*)alloc((size_t)NB * LL * CHN * 2);   // = in_hi
    unsigned short* wT_bf  = (unsigned short*)alloc((size_t)9 * CHN * CHN * 2);
    unsigned short* ya_bf  = (unsigned short*)alloc((size_t)NB * LL * CHN * 2);
    unsigned short* yaT    = (unsigned short*)alloc((size_t)NB * LL * CHN * 2);
    float* xm     = (float*)alloc((size_t)NB * LL * CC * 4);
    float* xmT    = (float*)alloc((size_t)NB * LL * CC * 4);
    unsigned short* xmT_bf = (unsigned short*)alloc((size_t)NB * LL * CC * 2);
    float* ssq    = (float*)alloc((size_t)NB * LL * 4);
    int*   codes  = (int*)  alloc((size_t)NB * NJ * 4);
    int*   rank   = (int*)  alloc((size_t)NB * NJ * 4);
    int*   hist   = (int*)  alloc((size_t)NB * NJ * 4);
    int*   sidx   = (int*)  alloc((size_t)NB * NJ * 4);
    int*   undo   = (int*)  alloc((size_t)NB * NJ * 4);
    float* bs     = (float*)alloc((size_t)NB * NJ * 4);
    unsigned short* Osort = (unsigned short*)alloc((size_t)NB * NJ * CHN * 2);
    unsigned short* wmT_hi = (unsigned short*)alloc((size_t)9 * 64 * CHN * 2);
    unsigned short* wmT_lo = (unsigned short*)alloc((size_t)9 * 64 * CHN * 2);
    // in_lo (18.9 MB) aliases the head of Osort (75.5 MB): in_lo is written by
    // cvt_in_hilo_k and last read by conv_match_mfma_k, both strictly before
    // attn_mfma_k writes Osort on the same stream.
    unsigned short* in_lo = Osort;

    // input hi/lo split (hi also feeds the value-path conv)
    cvt_in_hilo_k<<<dim3(4608), 256, 0, stream>>>(input, in_bf, in_lo);
    // match path (split-bf16 MFMA — feeds hashing at ~fp32 precision)
    cvt_wm_hilo_k<<<dim3(8, 2, 9), 256, 0, stream>>>(w_match, wmT_hi, wmT_lo);
    conv_match_mfma_k<<<dim3(144, 1, NB), 256, 0, stream>>>(in_bf, in_lo, wmT_hi, wmT_lo, b_match, xm);
    transpose_k<<<dim3(288, 2, NB), 256, 0, stream>>>(xm, xmT, xmT_bf, CC, LL);
    // value path (bf16 MFMA)
    cvt_wT_k<<<dim3(8, 8, 9), 256, 0, stream>>>(w_asm, wT_bf);
    conv_mfma_k<<<dim3(72, 2, NB), 256, 0, stream>>>(in_bf, wT_bf, b_asm, ya_bf);
    transpose_bf_k<<<dim3(144, 4, NB), 256, 0, stream>>>(ya_bf, yaT);
    // hashing + sort
    hash_k<<<dim3(144, NHASH), 256, 0, stream>>>(xmT, rot, codes, ssq);
    sort_hist_k<<<dim3(144, NB), 256, 0, stream>>>(codes, hist, rank);
    sort_scan_k<<<dim3(NB), 256, 0, stream>>>(hist);
    sort_scatter_k<<<dim3(144, NB), 256, 0, stream>>>(codes, rank, hist, sidx, undo);
    // attention + combine
    attn_mfma_k<<<dim3(NCHUNK, NHASH, NB), 1024, 0, stream>>>(xmT_bf, yaT, ssq, sidx, Osort, bs);
    combfin_k<<<dim3(288, NB), 256, 0, stream>>>(Osort, bs, undo, input, out);
}

// Round 12
// 397.559 us; speedup vs baseline: 1.4353x; 1.0912x over previous
//
#include <hip/hip_runtime.h>
#include <cstdint>
#include <cstddef>

#define NB 4
#define HH 96
#define WW 96
#define CHN 256
#define CC 64
#define LL 9216
#define NHASH 4
#define HBK 64
#define CHK 144
#define NCHUNK 64
#define NJ 36864   // NHASH * LL

typedef __attribute__((ext_vector_type(8))) short bf16x8;
typedef __attribute__((ext_vector_type(8))) unsigned short u16x8;
typedef __attribute__((ext_vector_type(4))) float f32x4;

__device__ __forceinline__ unsigned short f2b(float f) {
    unsigned int x = __float_as_uint(f);
    x += 0x7FFFu + ((x >> 16) & 1u);
    return (unsigned short)(x >> 16);
}
__device__ __forceinline__ float b2f(unsigned short u) {
    return __uint_as_float(((unsigned int)u) << 16);
}

// ---------------------------------------------------------------- input fp32 -> bf16 hi + bf16 lo residual
__global__ __launch_bounds__(256) void cvt_in_hilo_k(const float* __restrict__ in,
                                                     unsigned short* __restrict__ hi,
                                                     unsigned short* __restrict__ lo)
{
    size_t g = ((size_t)blockIdx.x * 256 + threadIdx.x) * 8;
    float4 v0 = *(const float4*)(in + g);
    float4 v1 = *(const float4*)(in + g + 4);
    float xs[8] = {v0.x, v0.y, v0.z, v0.w, v1.x, v1.y, v1.z, v1.w};
    u16x8 h, l;
#pragma unroll
    for (int i = 0; i < 8; i++) {
        unsigned short hv = f2b(xs[i]);
        h[i] = hv;
        l[i] = f2b(xs[i] - b2f(hv));
    }
    *(u16x8*)(hi + g) = h;
    *(u16x8*)(lo + g) = l;
}

// ---------------------------------------------------------------- fused weight prep: w_match hilo-T + w_asm T
// grid (8, 10, 9): by<2 -> wm hi/lo transpose (o0=by*32); by>=2 -> w_asm transpose (o0=(by-2)*32).
// Independent outputs; whole blocks take one branch (wave-uniform).
__global__ __launch_bounds__(256) void cvt_w_fused_k(const float* __restrict__ wm,
                                                     unsigned short* __restrict__ wmT_hi,
                                                     unsigned short* __restrict__ wmT_lo,
                                                     const float* __restrict__ wa,
                                                     unsigned short* __restrict__ wT)
{
    __shared__ float tl[32][33];
    const int tap = blockIdx.z;
    const int c0 = blockIdx.x * 32;
    const int tx = threadIdx.x & 31, ty0 = threadIdx.x >> 5;
    if (blockIdx.y < 2) {
        const int o0 = blockIdx.y * 32;
#pragma unroll
        for (int i = 0; i < 32; i += 8)
            tl[ty0 + i][tx] = wm[((size_t)tap * 256 + c0 + ty0 + i) * 64 + o0 + tx];
        __syncthreads();
#pragma unroll
        for (int i = 0; i < 32; i += 8) {
            float v = tl[tx][ty0 + i];
            unsigned short h = f2b(v);
            size_t o = ((size_t)tap * 64 + o0 + ty0 + i) * 256 + c0 + tx;
            wmT_hi[o] = h;
            wmT_lo[o] = f2b(v - b2f(h));
        }
    } else {
        const int o0 = (blockIdx.y - 2) * 32;
#pragma unroll
        for (int i = 0; i < 32; i += 8)
            tl[ty0 + i][tx] = wa[((size_t)tap * 256 + c0 + ty0 + i) * 256 + o0 + tx];
        __syncthreads();
#pragma unroll
        for (int i = 0; i < 32; i += 8)
            wT[((size_t)tap * 256 + o0 + ty0 + i) * 256 + c0 + tx] = f2b(tl[tx][ty0 + i]);
    }
}

// ---------------------------------------------------------------- FUSED MFMA convs (match split-bf16 + value bf16)
// Horizontal fusion: the two convs are data-independent (both read in_hi; match
// also reads in_lo). Run as ONE grid of 288 blocks/n (4.5 blocks/CU vs 2.25 each
// alone) so each path's load-latency bubbles are filled by the other's waves.
// One aliased 36.9KB LDS buffer (both layouts = 256*72 shorts). Inner loops are
// the verified round-10 bodies (ci-64 steps + compile-safe T14 prefetch,
// #pragma unroll 1). Branch is block-uniform -> no divergent barriers.
#define ASTR2 72
__global__ __launch_bounds__(256, 2) void convs_fused_k(
    const unsigned short* __restrict__ in_hi, const unsigned short* __restrict__ in_lo,
    const unsigned short* __restrict__ wmT_hi, const unsigned short* __restrict__ wmT_lo,
    const float* __restrict__ b_match, float* __restrict__ xm,
    const unsigned short* __restrict__ wT, const float* __restrict__ b_asm,
    unsigned short* __restrict__ ya_bf)
{
    __shared__ short smem[256 * ASTR2];   // 36.9KB, partitioned per path
    const int n = blockIdx.y;
    const int tid = threadIdx.x;
    const int w = tid >> 6;
    const int lane = tid & 63, lm = lane & 15, lq = lane >> 4;

    if (blockIdx.x < 144) {
        // ---------------- conv_match path: p0 = bx*64, all 64 co
        short* Ah = smem;
        short* Al = smem + 64 * ASTR2;
        short* Bh = smem + 128 * ASTR2;
        short* Bl = smem + 192 * ASTR2;
        const int p0 = blockIdx.x * 64;
        const int r = tid >> 2, q8 = (tid & 3) * 8;
        const int p = p0 + r, py = p / WW, px = p % WW;
        const unsigned short* hiN = in_hi + (size_t)n * LL * CHN;
        const unsigned short* loN = in_lo + (size_t)n * LL * CHN;

        f32x4 acc[4];
#pragma unroll
        for (int b = 0; b < 4; b++) acc[b] = (f32x4){0.f, 0.f, 0.f, 0.f};

        u16x8 avh0 = (u16x8){0,0,0,0,0,0,0,0}, avh1 = (u16x8){0,0,0,0,0,0,0,0};
        u16x8 avl0 = (u16x8){0,0,0,0,0,0,0,0}, avl1 = (u16x8){0,0,0,0,0,0,0,0};
        u16x8 bvh0, bvh1, bvl0, bvl1;
        {
            int sy = py - 1, sx = px - 1;
            if (((unsigned)sy < HH) && ((unsigned)sx < WW)) {
                size_t ao = (size_t)(sy * WW + sx) * CHN + q8;
                avh0 = *(const u16x8*)(hiN + ao);
                avh1 = *(const u16x8*)(hiN + ao + 32);
                avl0 = *(const u16x8*)(loN + ao);
                avl1 = *(const u16x8*)(loN + ao + 32);
            }
            size_t bo = (size_t)r * 256 + q8;
            bvh0 = *(const u16x8*)(wmT_hi + bo);
            bvh1 = *(const u16x8*)(wmT_hi + bo + 32);
            bvl0 = *(const u16x8*)(wmT_lo + bo);
            bvl1 = *(const u16x8*)(wmT_lo + bo + 32);
        }

#pragma unroll 1
        for (int it = 0; it < 36; it++) {
            __syncthreads();
            *(u16x8*)&Ah[r * ASTR2 + q8]      = avh0;
            *(u16x8*)&Ah[r * ASTR2 + q8 + 32] = avh1;
            *(u16x8*)&Al[r * ASTR2 + q8]      = avl0;
            *(u16x8*)&Al[r * ASTR2 + q8 + 32] = avl1;
            *(u16x8*)&Bh[r * ASTR2 + q8]      = bvh0;
            *(u16x8*)&Bh[r * ASTR2 + q8 + 32] = bvh1;
            *(u16x8*)&Bl[r * ASTR2 + q8]      = bvl0;
            *(u16x8*)&Bl[r * ASTR2 + q8 + 32] = bvl1;
            if (it < 35) {
                int nit = it + 1;
                int ntap = nit >> 2, nci = (nit & 3) << 6;
                int ky = ntap / 3, kx = ntap - ky * 3;
                int sy = py + ky - 1, sx = px + kx - 1;
                avh0 = (u16x8){0,0,0,0,0,0,0,0}; avh1 = (u16x8){0,0,0,0,0,0,0,0};
                avl0 = (u16x8){0,0,0,0,0,0,0,0}; avl1 = (u16x8){0,0,0,0,0,0,0,0};
                if (((unsigned)sy < HH) && ((unsigned)sx < WW)) {
                    size_t ao = (size_t)(sy * WW + sx) * CHN + q8 + nci;
                    avh0 = *(const u16x8*)(hiN + ao);
                    avh1 = *(const u16x8*)(hiN + ao + 32);
                    avl0 = *(const u16x8*)(loN + ao);
                    avl1 = *(const u16x8*)(loN + ao + 32);
                }
                size_t bo = ((size_t)ntap * 64 + r) * 256 + q8 + nci;
                bvh0 = *(const u16x8*)(wmT_hi + bo);
                bvh1 = *(const u16x8*)(wmT_hi + bo + 32);
                bvl0 = *(const u16x8*)(wmT_lo + bo);
                bvl1 = *(const u16x8*)(wmT_lo + bo + 32);
            }
            __syncthreads();
#pragma unroll
            for (int cs = 0; cs < 2; cs++) {
                bf16x8 afh = *(const bf16x8*)&Ah[(w * 16 + lm) * ASTR2 + cs * 32 + lq * 8];
                bf16x8 afl = *(const bf16x8*)&Al[(w * 16 + lm) * ASTR2 + cs * 32 + lq * 8];
#pragma unroll
                for (int nt = 0; nt < 4; nt++) {
                    bf16x8 bfh = *(const bf16x8*)&Bh[(nt * 16 + lm) * ASTR2 + cs * 32 + lq * 8];
                    bf16x8 bfl = *(const bf16x8*)&Bl[(nt * 16 + lm) * ASTR2 + cs * 32 + lq * 8];
                    acc[nt] = __builtin_amdgcn_mfma_f32_16x16x32_bf16(afh, bfh, acc[nt], 0, 0, 0);
                    acc[nt] = __builtin_amdgcn_mfma_f32_16x16x32_bf16(afh, bfl, acc[nt], 0, 0, 0);
                    acc[nt] = __builtin_amdgcn_mfma_f32_16x16x32_bf16(afl, bfh, acc[nt], 0, 0, 0);
                }
            }
        }
        float bvv[4];
#pragma unroll
        for (int nt = 0; nt < 4; nt++) bvv[nt] = b_match[nt * 16 + lm];
        float* outN = xm + (size_t)n * LL * 64;
#pragma unroll
        for (int r4 = 0; r4 < 4; r4++) {
            int row = p0 + w * 16 + lq * 4 + r4;
            float* od = outN + (size_t)row * 64;
#pragma unroll
            for (int nt = 0; nt < 4; nt++)
                od[nt * 16 + lm] = acc[nt][r4] + bvv[nt];
        }
    } else {
        // ---------------- conv_mfma (value) path: 128px x 128co tile
        short* As = smem;
        short* Bs = smem + 128 * ASTR2;
        const int idx = blockIdx.x - 144;
        const int co_blk = idx / 72;
        const int px_blk = idx - co_blk * 72;
        const int p0 = px_blk * 128, co0 = co_blk * 128;
        const int wr = w >> 1, wc = w & 1;
        const int r = tid >> 1, hf = tid & 1;
        const int p = p0 + r, py = p / WW, px = p % WW;
        const unsigned short* inN = in_hi + (size_t)n * LL * CHN;

        f32x4 acc[4][4];
#pragma unroll
        for (int a = 0; a < 4; a++)
#pragma unroll
            for (int b = 0; b < 4; b++) acc[a][b] = (f32x4){0.f, 0.f, 0.f, 0.f};

        u16x8 av0 = (u16x8){0,0,0,0,0,0,0,0}, av1 = (u16x8){0,0,0,0,0,0,0,0};
        u16x8 av2 = (u16x8){0,0,0,0,0,0,0,0}, av3 = (u16x8){0,0,0,0,0,0,0,0};
        u16x8 bv0, bv1, bv2, bv3;
        {
            int sy = py - 1, sx = px - 1;
            if (((unsigned)sy < HH) && ((unsigned)sx < WW)) {
                const unsigned short* asrc = inN + (size_t)(sy * WW + sx) * CHN + hf * 32;
                av0 = *(const u16x8*)(asrc);
                av1 = *(const u16x8*)(asrc + 8);
                av2 = *(const u16x8*)(asrc + 16);
                av3 = *(const u16x8*)(asrc + 24);
            }
            const unsigned short* bsrc = wT + ((size_t)co0 + r) * 256 + hf * 32;
            bv0 = *(const u16x8*)(bsrc);
            bv1 = *(const u16x8*)(bsrc + 8);
            bv2 = *(const u16x8*)(bsrc + 16);
            bv3 = *(const u16x8*)(bsrc + 24);
        }

#pragma unroll 1
        for (int it = 0; it < 36; it++) {
            __syncthreads();
            *(u16x8*)&As[r * ASTR2 + hf * 32]      = av0;
            *(u16x8*)&As[r * ASTR2 + hf * 32 + 8]  = av1;
            *(u16x8*)&As[r * ASTR2 + hf * 32 + 16] = av2;
            *(u16x8*)&As[r * ASTR2 + hf * 32 + 24] = av3;
            *(u16x8*)&Bs[r * ASTR2 + hf * 32]      = bv0;
            *(u16x8*)&Bs[r * ASTR2 + hf * 32 + 8]  = bv1;
            *(u16x8*)&Bs[r * ASTR2 + hf * 32 + 16] = bv2;
            *(u16x8*)&Bs[r * ASTR2 + hf * 32 + 24] = bv3;
            if (it < 35) {
                int nit = it + 1;
                int ntap = nit >> 2, nci = (nit & 3) << 6;
                int ky = ntap / 3, kx = ntap - ky * 3;
                int sy = py + ky - 1, sx = px + kx - 1;
                av0 = (u16x8){0,0,0,0,0,0,0,0}; av1 = (u16x8){0,0,0,0,0,0,0,0};
                av2 = (u16x8){0,0,0,0,0,0,0,0}; av3 = (u16x8){0,0,0,0,0,0,0,0};
                if (((unsigned)sy < HH) && ((unsigned)sx < WW)) {
                    const unsigned short* asrc = inN + (size_t)(sy * WW + sx) * CHN + hf * 32 + nci;
                    av0 = *(const u16x8*)(asrc);
                    av1 = *(const u16x8*)(asrc + 8);
                    av2 = *(const u16x8*)(asrc + 16);
                    av3 = *(const u16x8*)(asrc + 24);
                }
                const unsigned short* bsrc = wT + ((size_t)ntap * 256 + co0 + r) * 256 + hf * 32 + nci;
                bv0 = *(const u16x8*)(bsrc);
                bv1 = *(const u16x8*)(bsrc + 8);
                bv2 = *(const u16x8*)(bsrc + 16);
                bv3 = *(const u16x8*)(bsrc + 24);
            }
            __syncthreads();
#pragma unroll
            for (int cs = 0; cs < 2; cs++) {
                bf16x8 af[4], bf[4];
#pragma unroll
                for (int mt = 0; mt < 4; mt++)
                    af[mt] = *(const bf16x8*)&As[(wr * 64 + mt * 16 + lm) * ASTR2 + cs * 32 + lq * 8];
#pragma unroll
                for (int nt = 0; nt < 4; nt++)
                    bf[nt] = *(const bf16x8*)&Bs[(wc * 64 + nt * 16 + lm) * ASTR2 + cs * 32 + lq * 8];
#pragma unroll
                for (int mt = 0; mt < 4; mt++)
#pragma unroll
                    for (int nt = 0; nt < 4; nt++)
                        acc[mt][nt] = __builtin_amdgcn_mfma_f32_16x16x32_bf16(af[mt], bf[nt], acc[mt][nt], 0, 0, 0);
            }
        }
        float bv[4];
#pragma unroll
        for (int nt = 0; nt < 4; nt++) bv[nt] = b_asm[co0 + wc * 64 + nt * 16 + lm];
#pragma unroll
        for (int mt = 0; mt < 4; mt++) {
#pragma unroll
            for (int r4 = 0; r4 < 4; r4++) {
                int row = p0 + wr * 64 + mt * 16 + lq * 4 + r4;
                unsigned short* od = ya_bf + ((size_t)n * LL + row) * CHN + co0 + wc * 64;
#pragma unroll
                for (int nt = 0; nt < 4; nt++)
                    od[nt * 16 + lm] = f2b(acc[mt][nt][r4] + bv[nt]);
            }
        }
    }
}

// ---------------------------------------------------------------- FUSED transposes (fp32 match + bf16 value)
// Both are runnable immediately after convs_fused_k (xm and ya_bf both ready);
// fusing puts 2304 blocks/n in flight. Branch is block-uniform.
__global__ __launch_bounds__(256) void transposes_fused_k(
    const float* __restrict__ xm, float* __restrict__ xmT, unsigned short* __restrict__ xmT_bf,
    const unsigned short* __restrict__ ya_bf, unsigned short* __restrict__ yaT)
{
    __shared__ float tlf[32][33];
    __shared__ unsigned short tlb[64][65];
    const int n = blockIdx.y;
    if (blockIdx.x < 576) {
        // transpose_k: orig grid (288, 2): c0 = bx*32, r0 = by*32; R=64, Cc=9216
        const int idx = blockIdx.x;
        const int by = idx / 288, bx = idx - by * 288;
        const size_t base = (size_t)n * 64 * LL;
        const int c0 = bx * 32, r0 = by * 32;
        const int tx = threadIdx.x & 31, ty0 = threadIdx.x >> 5;
#pragma unroll
        for (int i = 0; i < 32; i += 8)
            tlf[ty0 + i][tx] = xm[base + (size_t)(r0 + ty0 + i) * LL + c0 + tx];
        __syncthreads();
#pragma unroll
        for (int i = 0; i < 32; i += 8) {
            float v = tlf[tx][ty0 + i];
            size_t o = base + (size_t)(c0 + ty0 + i) * 64 + r0 + tx;
            xmT[o] = v;
            xmT_bf[o] = f2b(v);
        }
    } else {
        // transpose_bf: orig grid (144, 4): t0 = bx*64, e0 = by*64
        const int idx = blockIdx.x - 576;
        const int by = idx / 144, bx = idx - by * 144;
        const size_t base = (size_t)n * LL * CHN;
        const int t0 = bx * 64, e0 = by * 64;
        const int tx = threadIdx.x & 63, ty0 = threadIdx.x >> 6;
#pragma unroll
        for (int i = 0; i < 16; i++) {
            int row = ty0 + i * 4;
            tlb[row][tx] = ya_bf[base + (size_t)(e0 + row) * LL + t0 + tx];
        }
        __syncthreads();
#pragma unroll
        for (int i = 0; i < 16; i++) {
            int row = ty0 + i * 4;
            yaT[base + (size_t)(t0 + row) * CHN + e0 + tx] = tlb[tx][row];
        }
    }
}

// ---------------------------------------------------------------- hashing: codes + squared norms (fp32!)
__global__ __launch_bounds__(256) void hash_k(const float* __restrict__ xmT, const float* __restrict__ rot,
                                              int* __restrict__ codes, float* __restrict__ ssq)
{
    __shared__ float rs[32 * 68];   // [i][f], stride 68, this block's hash only
    const int h = blockIdx.y;
    for (int e = threadIdx.x; e < 2048; e += 256) {
        int hi = e >> 6, f = e & 63;
        rs[hi * 68 + f] = rot[f * 128 + h * 32 + hi];
    }
    __syncthreads();
    int g = blockIdx.x * 256 + threadIdx.x;
    int n = g / LL, t = g % LL;
    float4 x4[16];
    const float* src = xmT + (size_t)g * CC;
#pragma unroll
    for (int f4 = 0; f4 < 16; f4++) x4[f4] = *(const float4*)(src + f4 * 4);
    if (h == 0) {
        float ss = 0.f;
#pragma unroll
        for (int f4 = 0; f4 < 16; f4++)
            ss += x4[f4].x * x4[f4].x + x4[f4].y * x4[f4].y + x4[f4].z * x4[f4].z + x4[f4].w * x4[f4].w;
        ssq[g] = ss;
    }
    float bp = -1e30f, bn = -1e30f;
    int ip = 0, inn = 0;
    for (int i = 0; i < 32; i++) {
        const float* rr = &rs[i * 68];
        float d0 = 0.f, d1 = 0.f, d2 = 0.f, d3 = 0.f;
#pragma unroll
        for (int f4 = 0; f4 < 16; f4++) {
            float4 r4 = *(const float4*)(rr + f4 * 4);
            d0 = fmaf(x4[f4].x, r4.x, d0);
            d1 = fmaf(x4[f4].y, r4.y, d1);
            d2 = fmaf(x4[f4].z, r4.z, d2);
            d3 = fmaf(x4[f4].w, r4.w, d3);
        }
        float d = (d0 + d1) + (d2 + d3);
        if (d > bp) { bp = d; ip = i; }
        if (-d > bn) { bn = -d; inn = i; }
    }
    int code = (bp >= bn) ? ip : (32 + inn);
    codes[(size_t)n * NJ + h * LL + t] = code + h * HBK;
}

// ---------------------------------------------------------------- stable counting sort (256 buckets)
__global__ __launch_bounds__(256) void sort_hist_k(const int* __restrict__ codes, int* __restrict__ hist,
                                                   int* __restrict__ rank)
{
    __shared__ int lhw[4][256];
    const int n = blockIdx.y, seg = blockIdx.x, tid = threadIdx.x;
    const int w = tid >> 6, lane = tid & 63;
    int j = seg * 256 + tid;
    int c = codes[(size_t)n * NJ + j];
    for (int e = tid; e < 1024; e += 256) ((int*)lhw)[e] = 0;
    __syncthreads();
    unsigned long long eq = ~0ull;
#pragma unroll
    for (int b = 0; b < 8; b++) {
        unsigned long long m = __ballot((c >> b) & 1);
        eq &= ((c >> b) & 1) ? m : ~m;
    }
    int rw = __popcll(eq & ((1ull << lane) - 1ull));   // rank within wave (tid order)
    int cntw = __popcll(eq);                           // class count in this wave
    if (rw == 0) lhw[w][c] = cntw;                     // unique (w,c) writer
    __syncthreads();
    int base = 0;
    if (w > 0) base += lhw[0][c];
    if (w > 1) base += lhw[1][c];
    if (w > 2) base += lhw[2][c];
    rank[(size_t)n * NJ + j] = base + rw;
    hist[(size_t)n * NJ + tid * 144 + seg] = lhw[0][tid] + lhw[1][tid] + lhw[2][tid] + lhw[3][tid];
}

__global__ __launch_bounds__(256) void sort_scan_k(int* __restrict__ hist)
{
    const int n = blockIdx.x;
    const int key = threadIdx.x;
    int* hn = hist + (size_t)n * NJ;
    int sum = 0;
    for (int s = 0; s < 144; s++) sum += hn[key * 144 + s];
    __shared__ int sc[256];
    sc[key] = sum;
    __syncthreads();
    for (int off = 1; off < 256; off <<= 1) {
        int v = (key >= off) ? sc[key - off] : 0;
        __syncthreads();
        sc[key] += v;
        __syncthreads();
    }
    int run = sc[key] - sum;   // exclusive prefix
    for (int s = 0; s < 144; s++) { int v = hn[key * 144 + s]; hn[key * 144 + s] = run; run += v; }
}

__global__ __launch_bounds__(256) void sort_scatter_k(const int* __restrict__ codes, const int* __restrict__ rank,
                                                      const int* __restrict__ hist, int* __restrict__ sidx,
                                                      int* __restrict__ undo)
{
    const int n = blockIdx.y, seg = blockIdx.x, tid = threadIdx.x;
    int j = seg * 256 + tid;
    int c = codes[(size_t)n * NJ + j];
    int dest = hist[(size_t)n * NJ + c * 144 + seg] + rank[(size_t)n * NJ + j];
    sidx[(size_t)n * NJ + dest] = j;
    undo[(size_t)n * NJ + j] = dest;
}

// ---------------------------------------------------------------- MFMA attention v5 (verified 124us — unchanged)
#define QSTR 72     // Q/K row stride in shorts
#define PSTR 164    // P row stride in shorts (conflict-free write quadrants)
__global__ __launch_bounds__(1024, 4) __attribute__((amdgpu_waves_per_eu(4, 4))) void attn_mfma_k(
    const unsigned short* __restrict__ xmT_bf, const unsigned short* __restrict__ yaT,
    const float* __restrict__ ssq, const int* __restrict__ sidx,
    unsigned short* __restrict__ Osort, float* __restrict__ bs)
{
    __shared__ short Qs[144 * QSTR];
    __shared__ short Ks[144 * QSTR];
    __shared__ short Ps[144 * PSTR];
    __shared__ int   tIdx[432];
    __shared__ int   voff[432];
    __shared__ float nfs[432];
    __shared__ float qlen[432];
    __shared__ float lsum[144];
    __shared__ float linv[144];

    const int k = blockIdx.x, h = blockIdx.y, n = blockIdx.z;
    const int tid = threadIdx.x;
    const int w = tid >> 6, lane = tid & 63;
    const int lm = lane & 15, lq = lane >> 4;
    const size_t sbase = (size_t)n * NJ + (size_t)h * LL;

    if (tid < 432) {
        int cc = tid / CHK, rr = tid - cc * CHK;
        int c = (cc == 0) ? k : (cc == 1 ? (k + NCHUNK - 1) & (NCHUNK - 1) : (k + 1) & (NCHUNK - 1));
        int j = sidx[sbase + c * CHK + rr];
        int t = j % LL;
        tIdx[tid] = t;
        voff[tid] = t * (CHN * 2);
        float m = fmaxf(ssq[(size_t)n * LL + t], 5e-5f);
        float nf = rsqrtf(m);
        nfs[tid] = nf;
        qlen[tid] = m * nf;   // sqrt(m) = |q| clamped
    }
    __syncthreads();   // tIdx/voff/nfs/qlen ready

    // stage Q rows (raw bf16)
    const int sr = tid >> 3, sj = (tid & 7) * 8;
    const int sr2 = (tid + 1024) >> 3, sj2 = (tid & 7) * 8;
    {
        u16x8 v = *(const u16x8*)(xmT_bf + ((size_t)n * LL + tIdx[sr]) * CC + sj);
        *(u16x8*)&Qs[sr * QSTR + sj] = v;
        if (tid < 128) {
            u16x8 v2 = *(const u16x8*)(xmT_bf + ((size_t)n * LL + tIdx[sr2]) * CC + sj2);
            *(u16x8*)&Qs[sr2 * QSTR + sj2] = v2;
        }
    }
    // zero P pad columns 144..159 once (P writes later touch cols 0..143 only)
    for (int e = tid; e < 2304; e += 1024) {
        int r = e >> 4, c = 144 + (e & 15);
        Ps[r * PSTR + c] = 0;
    }
    // T14: issue chunk-1 K loads into registers now (consumed at top of chunk 1)
    u16x8 kreg0, kreg1;
    kreg0 = *(const u16x8*)(xmT_bf + ((size_t)n * LL + tIdx[CHK + sr]) * CC + sj);
    if (tid < 128)
        kreg1 = *(const u16x8*)(xmT_bf + ((size_t)n * LL + tIdx[CHK + sr2]) * CC + sj2);

    const char* vbase = (const char*)(yaT + (size_t)n * LL * CHN + w * 16 + lm);
    f32x4 accO[9];
#pragma unroll
    for (int mt = 0; mt < 9; mt++) accO[mt] = (f32x4){0.f, 0.f, 0.f, 0.f};
    f32x4 accL = (f32x4){0.f, 0.f, 0.f, 0.f};
    bf16x8 onesF, onesL;
#pragma unroll
    for (int i = 0; i < 8; i++) {
        onesF[i] = (short)0x3F80;
        onesL[i] = (lq < 2) ? (short)0x3F80 : (short)0;   // mask pad keys 144..159 (k-step 4, lq>=2)
    }

    for (int cc = 0; cc < 3; cc++) {
        const int c144 = cc * CHK;
        if (cc > 0) {
            *(u16x8*)&Ks[sr * QSTR + sj] = kreg0;
            if (tid < 128) *(u16x8*)&Ks[sr2 * QSTR + sj2] = kreg1;
        }
        if (cc < 2) {
            kreg0 = *(const u16x8*)(xmT_bf + ((size_t)n * LL + tIdx[(cc + 1) * CHK + sr]) * CC + sj);
            if (tid < 128)
                kreg1 = *(const u16x8*)(xmT_bf + ((size_t)n * LL + tIdx[(cc + 1) * CHK + sr2]) * CC + sj2);
        }
        // V B-frag gathers from global — issued early, consumed after QK (latency hidden)
        bf16x8 vfrag[5];
#pragma unroll
        for (int ks = 0; ks < 5; ks++) {
            int kb = ks * 32 + lq * 8;
            if (kb < 144) {
                int4 o0 = *(const int4*)&voff[c144 + kb];
                int4 o1 = *(const int4*)&voff[c144 + kb + 4];
                vfrag[ks][0] = (short)*(const unsigned short*)(vbase + o0.x);
                vfrag[ks][1] = (short)*(const unsigned short*)(vbase + o0.y);
                vfrag[ks][2] = (short)*(const unsigned short*)(vbase + o0.z);
                vfrag[ks][3] = (short)*(const unsigned short*)(vbase + o0.w);
                vfrag[ks][4] = (short)*(const unsigned short*)(vbase + o1.x);
                vfrag[ks][5] = (short)*(const unsigned short*)(vbase + o1.y);
                vfrag[ks][6] = (short)*(const unsigned short*)(vbase + o1.z);
                vfrag[ks][7] = (short)*(const unsigned short*)(vbase + o1.w);
            } else {
                vfrag[ks] = (bf16x8){0, 0, 0, 0, 0, 0, 0, 0};
            }
        }
        __syncthreads();

        // QK (B^T GEMM) + exp; raw scores post-scaled by key norm; P written straight to LDS
        const short* Bsrc = (cc == 0) ? Qs : Ks;
        for (int tt = w; tt < 81; tt += 16) {
            int mt = tt / 9, nt = tt - mt * 9;
            f32x4 c = {0.f, 0.f, 0.f, 0.f};
#pragma unroll
            for (int ks = 0; ks < 2; ks++) {
                bf16x8 a = *(const bf16x8*)&Qs[(mt * 16 + lm) * QSTR + ks * 32 + lq * 8];
                bf16x8 b = *(const bf16x8*)&Bsrc[(nt * 16 + lm) * QSTR + ks * 32 + lq * 8];
                c = __builtin_amdgcn_mfma_f32_16x16x32_bf16(a, b, c, 0, 0, 0);
            }
            float nfk = nfs[c144 + nt * 16 + lm];
#pragma unroll
            for (int r = 0; r < 4; r++) {
                int mrow = mt * 16 + lq * 4 + r;
                float p = __expf(fmaf(c[r], nfk, -qlen[mrow]));
                Ps[mrow * PSTR + nt * 16 + lm] = (short)f2b(p);
            }
        }
        __syncthreads();   // Ps ready (pad cols are permanent zeros)

        // lsum via ones-MFMA (waves 0..8, mt = w)
        if (w < 9) {
#pragma unroll
            for (int ks = 0; ks < 5; ks++) {
                bf16x8 a = *(const bf16x8*)&Ps[(w * 16 + lm) * PSTR + ks * 32 + lq * 8];
                accL = __builtin_amdgcn_mfma_f32_16x16x32_bf16(a, (ks == 4) ? onesL : onesF, accL, 0, 0, 0);
            }
        }
        // PV: 9 m-tiles, V frags in registers
#pragma unroll
        for (int mt = 0; mt < 9; mt++) {
            f32x4 c = accO[mt];
#pragma unroll
            for (int ks = 0; ks < 5; ks++) {
                bf16x8 a = *(const bf16x8*)&Ps[(mt * 16 + lm) * PSTR + ks * 32 + lq * 8];
                c = __builtin_amdgcn_mfma_f32_16x16x32_bf16(a, vfrag[ks], c, 0, 0, 0);
            }
            accO[mt] = c;
        }
    }

    if (w < 9 && lm == 0) {
#pragma unroll
        for (int r = 0; r < 4; r++) lsum[w * 16 + lq * 4 + r] = accL[r];
    }
    __syncthreads();
    if (tid < 144) {
        float l = lsum[tid];
        linv[tid] = 1.0f / l;
        bs[sbase + tIdx[tid]] = qlen[tid] + __logf(l);
    }
    __syncthreads();

#pragma unroll
    for (int mt = 0; mt < 9; mt++) {
        f32x4 c = accO[mt];
#pragma unroll
        for (int r = 0; r < 4; r++) {
            int mrow = mt * 16 + lq * 4 + r;
            Osort[(sbase + (size_t)k * CHK + mrow) * CHN + w * 16 + lm] = f2b(c[r] * linv[mrow]);
        }
    }
}

// ---------------------------------------------------------------- combine (4 hashes, inline softmax) + transpose + residual
__global__ __launch_bounds__(256) void combfin_k(
    const unsigned short* __restrict__ Osort, const float* __restrict__ bs,
    const int* __restrict__ undo, const float* __restrict__ inp, float* __restrict__ out)
{
    __shared__ float ac[32][260];
    __shared__ int   uS[4][32];
    __shared__ float pS[4][32];
    const int n = blockIdx.y;
    const int t0 = blockIdx.x * 32;
    const int tid = threadIdx.x;
    if (tid < 128) {
        int hh = tid >> 5, tt = tid & 31;
        size_t idx = (size_t)n * NJ + (size_t)hh * LL + t0 + tt;
        uS[hh][tt] = undo[idx];
        pS[hh][tt] = bs[idx];
    }
    __syncthreads();
    if (tid < 32) {
        float b0 = pS[0][tid], b1 = pS[1][tid], b2 = pS[2][tid], b3 = pS[3][tid];
        float mx = fmaxf(fmaxf(b0, b1), fmaxf(b2, b3));
        float e0 = __expf(b0 - mx), e1 = __expf(b1 - mx), e2 = __expf(b2 - mx), e3 = __expf(b3 - mx);
        float inv = 1.f / (e0 + e1 + e2 + e3);
        pS[0][tid] = e0 * inv; pS[1][tid] = e1 * inv; pS[2][tid] = e2 * inv; pS[3][tid] = e3 * inv;
    }
    __syncthreads();
    const int g = tid & 63, tq = tid >> 6;
    for (int tt8 = 0; tt8 < 8; tt8++) {
        int t = tq * 8 + tt8;
        float a0 = 0.f, a1 = 0.f, a2 = 0.f, a3 = 0.f;
#pragma unroll
        for (int hh = 0; hh < 4; hh++) {
            int row = uS[hh][t];
            float p = pS[hh][t];
            ushort4 u = *(const ushort4*)&Osort[((size_t)n * NJ + row) * CHN + g * 4];
            a0 = fmaf(p, b2f(u.x), a0);
            a1 = fmaf(p, b2f(u.y), a1);
            a2 = fmaf(p, b2f(u.z), a2);
            a3 = fmaf(p, b2f(u.w), a3);
        }
        *(float4*)&ac[t][g * 4] = make_float4(a0, a1, a2, a3);
    }
    __syncthreads();
    const int tp = tid & 31, er = tid >> 5;
    const float* inN = inp + (size_t)n * LL * CHN;
    float* outN = out + (size_t)n * LL * CHN;
    for (int it = 0; it < 32; it++) {
        int e = er + it * 8;
        size_t o = (size_t)e * LL + t0 + tp;
        outN[o] = ac[tp][e] * 0.1f + inN[o];
    }
}

// ---------------------------------------------------------------- launch
extern "C" void kernel_launch(void* const* d_in, const int* in_sizes, int n_in,
                              void* d_out, int out_size, void* d_ws, size_t ws_size,
                              hipStream_t stream)
{
    (void)in_sizes; (void)n_in; (void)out_size; (void)ws_size;
    const float* input   = (const float*)d_in[0];
    const float* w_match = (const float*)d_in[1];
    const float* b_match = (const float*)d_in[2];
    const float* w_asm   = (const float*)d_in[3];
    const float* b_asm   = (const float*)d_in[4];
    const float* rot     = (const float*)d_in[5];
    float* out = (float*)d_out;

    char* ws = (char*)d_ws;
    size_t off = 0;
    auto alloc = [&](size_t bytes) -> void* {
        void* p = ws + off;
        off += (bytes + 255) & ~(size_t)255;
        return p;
    };
    unsigned short* in_bf  = (unsigned short*)alloc((size_t)NB * LL * CHN * 2);   // = in_hi
    unsigned short* wT_bf  = (unsigned short*)alloc((size_t)9 * CHN * CHN * 2);
    unsigned short* ya_bf  = (unsigned short*)alloc((size_t)NB * LL * CHN * 2);
    unsigned short* yaT    = (unsigned short*)alloc((size_t)NB * LL * CHN * 2);
    float* xm     = (float*)alloc((size_t)NB * LL * CC * 4);
    float* xmT    = (float*)alloc((size_t)NB * LL * CC * 4);
    unsigned short* xmT_bf = (unsigned short*)alloc((size_t)NB * LL * CC * 2);
    float* ssq    = (float*)alloc((size_t)NB * LL * 4);
    int*   codes  = (int*)  alloc((size_t)NB * NJ * 4);
    int*   rank   = (int*)  alloc((size_t)NB * NJ * 4);
    int*   hist   = (int*)  alloc((size_t)NB * NJ * 4);
    int*   sidx   = (int*)  alloc((size_t)NB * NJ * 4);
    int*   undo   = (int*)  alloc((size_t)NB * NJ * 4);
    float* bs     = (float*)alloc((size_t)NB * NJ * 4);
    unsigned short* Osort = (unsigned short*)alloc((size_t)NB * NJ * CHN * 2);
    unsigned short* wmT_hi = (unsigned short*)alloc((size_t)9 * 64 * CHN * 2);
    unsigned short* wmT_lo = (unsigned short*)alloc((size_t)9 * 64 * CHN * 2);
    // in_lo (18.9 MB) aliases the head of Osort (75.5 MB): in_lo is written by
    // cvt_in_hilo_k and last read by convs_fused_k, both strictly before
    // attn_mfma_k writes Osort on the same stream.
    unsigned short* in_lo = Osort;

    // input hi/lo split (hi also feeds the value-path conv)
    cvt_in_hilo_k<<<dim3(4608), 256, 0, stream>>>(input, in_bf, in_lo);
    // fused weight prep (match hi/lo + asm transpose)
    cvt_w_fused_k<<<dim3(8, 10, 9), 256, 0, stream>>>(w_match, wmT_hi, wmT_lo, w_asm, wT_bf);
    // fused convs (match split-bf16 + value bf16) — 288 blocks/n
    convs_fused_k<<<dim3(288, NB), 256, 0, stream>>>(in_bf, in_lo, wmT_hi, wmT_lo, b_match, xm,
                                                     wT_bf, b_asm, ya_bf);
    // fused transposes (xm -> xmT/xmT_bf, ya_bf -> yaT) — 1152 blocks/n
    transposes_fused_k<<<dim3(1152, NB), 256, 0, stream>>>(xm, xmT, xmT_bf, ya_bf, yaT);
    // hashing + sort
    hash_k<<<dim3(144, NHASH), 256, 0, stream>>>(xmT, rot, codes, ssq);
    sort_hist_k<<<dim3(144, NB), 256, 0, stream>>>(codes, hist, rank);
    sort_scan_k<<<dim3(NB), 256, 0, stream>>>(hist);
    sort_scatter_k<<<dim3(144, NB), 256, 0, stream>>>(codes, rank, hist, sidx, undo);
    // attention + combine
    attn_mfma_k<<<dim3(NCHUNK, NHASH, NB), 1024, 0, stream>>>(xmT_bf, yaT, ssq, sidx, Osort, bs);
    combfin_k<<<dim3(288, NB), 256, 0, stream>>>(Osort, bs, undo, input, out);
}

// Round 13
// 393.056 us; speedup vs baseline: 1.4517x; 1.0115x over previous
//
#include <hip/hip_runtime.h>
#include <cstdint>
#include <cstddef>

#define NB 4
#define HH 96
#define WW 96
#define CHN 256
#define CC 64
#define LL 9216
#define NHASH 4
#define HBK 64
#define CHK 144
#define NCHUNK 64
#define NJ 36864   // NHASH * LL

typedef __attribute__((ext_vector_type(8))) short bf16x8;
typedef __attribute__((ext_vector_type(8))) unsigned short u16x8;
typedef __attribute__((ext_vector_type(4))) float f32x4;

__device__ __forceinline__ unsigned short f2b(float f) {
    unsigned int x = __float_as_uint(f);
    x += 0x7FFFu + ((x >> 16) & 1u);
    return (unsigned short)(x >> 16);
}
__device__ __forceinline__ float b2f(unsigned short u) {
    return __uint_as_float(((unsigned int)u) << 16);
}

// ---------------------------------------------------------------- input fp32 -> bf16 hi + bf16 lo residual
__global__ __launch_bounds__(256) void cvt_in_hilo_k(const float* __restrict__ in,
                                                     unsigned short* __restrict__ hi,
                                                     unsigned short* __restrict__ lo)
{
    size_t g = ((size_t)blockIdx.x * 256 + threadIdx.x) * 8;
    float4 v0 = *(const float4*)(in + g);
    float4 v1 = *(const float4*)(in + g + 4);
    float xs[8] = {v0.x, v0.y, v0.z, v0.w, v1.x, v1.y, v1.z, v1.w};
    u16x8 h, l;
#pragma unroll
    for (int i = 0; i < 8; i++) {
        unsigned short hv = f2b(xs[i]);
        h[i] = hv;
        l[i] = f2b(xs[i] - b2f(hv));
    }
    *(u16x8*)(hi + g) = h;
    *(u16x8*)(lo + g) = l;
}

// ---------------------------------------------------------------- fused weight prep: w_match hilo-T + w_asm T
__global__ __launch_bounds__(256) void cvt_w_fused_k(const float* __restrict__ wm,
                                                     unsigned short* __restrict__ wmT_hi,
                                                     unsigned short* __restrict__ wmT_lo,
                                                     const float* __restrict__ wa,
                                                     unsigned short* __restrict__ wT)
{
    __shared__ float tl[32][33];
    const int tap = blockIdx.z;
    const int c0 = blockIdx.x * 32;
    const int tx = threadIdx.x & 31, ty0 = threadIdx.x >> 5;
    if (blockIdx.y < 2) {
        const int o0 = blockIdx.y * 32;
#pragma unroll
        for (int i = 0; i < 32; i += 8)
            tl[ty0 + i][tx] = wm[((size_t)tap * 256 + c0 + ty0 + i) * 64 + o0 + tx];
        __syncthreads();
#pragma unroll
        for (int i = 0; i < 32; i += 8) {
            float v = tl[tx][ty0 + i];
            unsigned short h = f2b(v);
            size_t o = ((size_t)tap * 64 + o0 + ty0 + i) * 256 + c0 + tx;
            wmT_hi[o] = h;
            wmT_lo[o] = f2b(v - b2f(h));
        }
    } else {
        const int o0 = (blockIdx.y - 2) * 32;
#pragma unroll
        for (int i = 0; i < 32; i += 8)
            tl[ty0 + i][tx] = wa[((size_t)tap * 256 + c0 + ty0 + i) * 256 + o0 + tx];
        __syncthreads();
#pragma unroll
        for (int i = 0; i < 32; i += 8)
            wT[((size_t)tap * 256 + o0 + ty0 + i) * 256 + c0 + tx] = f2b(tl[tx][ty0 + i]);
    }
}

// ---------------------------------------------------------------- FUSED MFMA convs (match split-bf16 + value bf16)
#define ASTR2 72
__global__ __launch_bounds__(256, 2) void convs_fused_k(
    const unsigned short* __restrict__ in_hi, const unsigned short* __restrict__ in_lo,
    const unsigned short* __restrict__ wmT_hi, const unsigned short* __restrict__ wmT_lo,
    const float* __restrict__ b_match, float* __restrict__ xm,
    const unsigned short* __restrict__ wT, const float* __restrict__ b_asm,
    unsigned short* __restrict__ ya_bf)
{
    __shared__ short smem[256 * ASTR2];   // 36.9KB, partitioned per path
    const int n = blockIdx.y;
    const int tid = threadIdx.x;
    const int w = tid >> 6;
    const int lane = tid & 63, lm = lane & 15, lq = lane >> 4;

    if (blockIdx.x < 144) {
        // ---------------- conv_match path: p0 = bx*64, all 64 co
        short* Ah = smem;
        short* Al = smem + 64 * ASTR2;
        short* Bh = smem + 128 * ASTR2;
        short* Bl = smem + 192 * ASTR2;
        const int p0 = blockIdx.x * 64;
        const int r = tid >> 2, q8 = (tid & 3) * 8;
        const int p = p0 + r, py = p / WW, px = p % WW;
        const unsigned short* hiN = in_hi + (size_t)n * LL * CHN;
        const unsigned short* loN = in_lo + (size_t)n * LL * CHN;

        f32x4 acc[4];
#pragma unroll
        for (int b = 0; b < 4; b++) acc[b] = (f32x4){0.f, 0.f, 0.f, 0.f};

        u16x8 avh0 = (u16x8){0,0,0,0,0,0,0,0}, avh1 = (u16x8){0,0,0,0,0,0,0,0};
        u16x8 avl0 = (u16x8){0,0,0,0,0,0,0,0}, avl1 = (u16x8){0,0,0,0,0,0,0,0};
        u16x8 bvh0, bvh1, bvl0, bvl1;
        {
            int sy = py - 1, sx = px - 1;
            if (((unsigned)sy < HH) && ((unsigned)sx < WW)) {
                size_t ao = (size_t)(sy * WW + sx) * CHN + q8;
                avh0 = *(const u16x8*)(hiN + ao);
                avh1 = *(const u16x8*)(hiN + ao + 32);
                avl0 = *(const u16x8*)(loN + ao);
                avl1 = *(const u16x8*)(loN + ao + 32);
            }
            size_t bo = (size_t)r * 256 + q8;
            bvh0 = *(const u16x8*)(wmT_hi + bo);
            bvh1 = *(const u16x8*)(wmT_hi + bo + 32);
            bvl0 = *(const u16x8*)(wmT_lo + bo);
            bvl1 = *(const u16x8*)(wmT_lo + bo + 32);
        }

#pragma unroll 1
        for (int it = 0; it < 36; it++) {
            __syncthreads();
            *(u16x8*)&Ah[r * ASTR2 + q8]      = avh0;
            *(u16x8*)&Ah[r * ASTR2 + q8 + 32] = avh1;
            *(u16x8*)&Al[r * ASTR2 + q8]      = avl0;
            *(u16x8*)&Al[r * ASTR2 + q8 + 32] = avl1;
            *(u16x8*)&Bh[r * ASTR2 + q8]      = bvh0;
            *(u16x8*)&Bh[r * ASTR2 + q8 + 32] = bvh1;
            *(u16x8*)&Bl[r * ASTR2 + q8]      = bvl0;
            *(u16x8*)&Bl[r * ASTR2 + q8 + 32] = bvl1;
            if (it < 35) {
                int nit = it + 1;
                int ntap = nit >> 2, nci = (nit & 3) << 6;
                int ky = ntap / 3, kx = ntap - ky * 3;
                int sy = py + ky - 1, sx = px + kx - 1;
                avh0 = (u16x8){0,0,0,0,0,0,0,0}; avh1 = (u16x8){0,0,0,0,0,0,0,0};
                avl0 = (u16x8){0,0,0,0,0,0,0,0}; avl1 = (u16x8){0,0,0,0,0,0,0,0};
                if (((unsigned)sy < HH) && ((unsigned)sx < WW)) {
                    size_t ao = (size_t)(sy * WW + sx) * CHN + q8 + nci;
                    avh0 = *(const u16x8*)(hiN + ao);
                    avh1 = *(const u16x8*)(hiN + ao + 32);
                    avl0 = *(const u16x8*)(loN + ao);
                    avl1 = *(const u16x8*)(loN + ao + 32);
                }
                size_t bo = ((size_t)ntap * 64 + r) * 256 + q8 + nci;
                bvh0 = *(const u16x8*)(wmT_hi + bo);
                bvh1 = *(const u16x8*)(wmT_hi + bo + 32);
                bvl0 = *(const u16x8*)(wmT_lo + bo);
                bvl1 = *(const u16x8*)(wmT_lo + bo + 32);
            }
            __syncthreads();
#pragma unroll
            for (int cs = 0; cs < 2; cs++) {
                bf16x8 afh = *(const bf16x8*)&Ah[(w * 16 + lm) * ASTR2 + cs * 32 + lq * 8];
                bf16x8 afl = *(const bf16x8*)&Al[(w * 16 + lm) * ASTR2 + cs * 32 + lq * 8];
#pragma unroll
                for (int nt = 0; nt < 4; nt++) {
                    bf16x8 bfh = *(const bf16x8*)&Bh[(nt * 16 + lm) * ASTR2 + cs * 32 + lq * 8];
                    bf16x8 bfl = *(const bf16x8*)&Bl[(nt * 16 + lm) * ASTR2 + cs * 32 + lq * 8];
                    acc[nt] = __builtin_amdgcn_mfma_f32_16x16x32_bf16(afh, bfh, acc[nt], 0, 0, 0);
                    acc[nt] = __builtin_amdgcn_mfma_f32_16x16x32_bf16(afh, bfl, acc[nt], 0, 0, 0);
                    acc[nt] = __builtin_amdgcn_mfma_f32_16x16x32_bf16(afl, bfh, acc[nt], 0, 0, 0);
                }
            }
        }
        float bvv[4];
#pragma unroll
        for (int nt = 0; nt < 4; nt++) bvv[nt] = b_match[nt * 16 + lm];
        float* outN = xm + (size_t)n * LL * 64;
#pragma unroll
        for (int r4 = 0; r4 < 4; r4++) {
            int row = p0 + w * 16 + lq * 4 + r4;
            float* od = outN + (size_t)row * 64;
#pragma unroll
            for (int nt = 0; nt < 4; nt++)
                od[nt * 16 + lm] = acc[nt][r4] + bvv[nt];
        }
    } else {
        // ---------------- conv_mfma (value) path: 128px x 128co tile
        short* As = smem;
        short* Bs = smem + 128 * ASTR2;
        const int idx = blockIdx.x - 144;
        const int co_blk = idx / 72;
        const int px_blk = idx - co_blk * 72;
        const int p0 = px_blk * 128, co0 = co_blk * 128;
        const int wr = w >> 1, wc = w & 1;
        const int r = tid >> 1, hf = tid & 1;
        const int p = p0 + r, py = p / WW, px = p % WW;
        const unsigned short* inN = in_hi + (size_t)n * LL * CHN;

        f32x4 acc[4][4];
#pragma unroll
        for (int a = 0; a < 4; a++)
#pragma unroll
            for (int b = 0; b < 4; b++) acc[a][b] = (f32x4){0.f, 0.f, 0.f, 0.f};

        u16x8 av0 = (u16x8){0,0,0,0,0,0,0,0}, av1 = (u16x8){0,0,0,0,0,0,0,0};
        u16x8 av2 = (u16x8){0,0,0,0,0,0,0,0}, av3 = (u16x8){0,0,0,0,0,0,0,0};
        u16x8 bv0, bv1, bv2, bv3;
        {
            int sy = py - 1, sx = px - 1;
            if (((unsigned)sy < HH) && ((unsigned)sx < WW)) {
                const unsigned short* asrc = inN + (size_t)(sy * WW + sx) * CHN + hf * 32;
                av0 = *(const u16x8*)(asrc);
                av1 = *(const u16x8*)(asrc + 8);
                av2 = *(const u16x8*)(asrc + 16);
                av3 = *(const u16x8*)(asrc + 24);
            }
            const unsigned short* bsrc = wT + ((size_t)co0 + r) * 256 + hf * 32;
            bv0 = *(const u16x8*)(bsrc);
            bv1 = *(const u16x8*)(bsrc + 8);
            bv2 = *(const u16x8*)(bsrc + 16);
            bv3 = *(const u16x8*)(bsrc + 24);
        }

#pragma unroll 1
        for (int it = 0; it < 36; it++) {
            __syncthreads();
            *(u16x8*)&As[r * ASTR2 + hf * 32]      = av0;
            *(u16x8*)&As[r * ASTR2 + hf * 32 + 8]  = av1;
            *(u16x8*)&As[r * ASTR2 + hf * 32 + 16] = av2;
            *(u16x8*)&As[r * ASTR2 + hf * 32 + 24] = av3;
            *(u16x8*)&Bs[r * ASTR2 + hf * 32]      = bv0;
            *(u16x8*)&Bs[r * ASTR2 + hf * 32 + 8]  = bv1;
            *(u16x8*)&Bs[r * ASTR2 + hf * 32 + 16] = bv2;
            *(u16x8*)&Bs[r * ASTR2 + hf * 32 + 24] = bv3;
            if (it < 35) {
                int nit = it + 1;
                int ntap = nit >> 2, nci = (nit & 3) << 6;
                int ky = ntap / 3, kx = ntap - ky * 3;
                int sy = py + ky - 1, sx = px + kx - 1;
                av0 = (u16x8){0,0,0,0,0,0,0,0}; av1 = (u16x8){0,0,0,0,0,0,0,0};
                av2 = (u16x8){0,0,0,0,0,0,0,0}; av3 = (u16x8){0,0,0,0,0,0,0,0};
                if (((unsigned)sy < HH) && ((unsigned)sx < WW)) {
                    const unsigned short* asrc = inN + (size_t)(sy * WW + sx) * CHN + hf * 32 + nci;
                    av0 = *(const u16x8*)(asrc);
                    av1 = *(const u16x8*)(asrc + 8);
                    av2 = *(const u16x8*)(asrc + 16);
                    av3 = *(const u16x8*)(asrc + 24);
                }
                const unsigned short* bsrc = wT + ((size_t)ntap * 256 + co0 + r) * 256 + hf * 32 + nci;
                bv0 = *(const u16x8*)(bsrc);
                bv1 = *(const u16x8*)(bsrc + 8);
                bv2 = *(const u16x8*)(bsrc + 16);
                bv3 = *(const u16x8*)(bsrc + 24);
            }
            __syncthreads();
#pragma unroll
            for (int cs = 0; cs < 2; cs++) {
                bf16x8 af[4], bf[4];
#pragma unroll
                for (int mt = 0; mt < 4; mt++)
                    af[mt] = *(const bf16x8*)&As[(wr * 64 + mt * 16 + lm) * ASTR2 + cs * 32 + lq * 8];
#pragma unroll
                for (int nt = 0; nt < 4; nt++)
                    bf[nt] = *(const bf16x8*)&Bs[(wc * 64 + nt * 16 + lm) * ASTR2 + cs * 32 + lq * 8];
#pragma unroll
                for (int mt = 0; mt < 4; mt++)
#pragma unroll
                    for (int nt = 0; nt < 4; nt++)
                        acc[mt][nt] = __builtin_amdgcn_mfma_f32_16x16x32_bf16(af[mt], bf[nt], acc[mt][nt], 0, 0, 0);
            }
        }
        float bv[4];
#pragma unroll
        for (int nt = 0; nt < 4; nt++) bv[nt] = b_asm[co0 + wc * 64 + nt * 16 + lm];
#pragma unroll
        for (int mt = 0; mt < 4; mt++) {
#pragma unroll
            for (int r4 = 0; r4 < 4; r4++) {
                int row = p0 + wr * 64 + mt * 16 + lq * 4 + r4;
                unsigned short* od = ya_bf + ((size_t)n * LL + row) * CHN + co0 + wc * 64;
#pragma unroll
                for (int nt = 0; nt < 4; nt++)
                    od[nt * 16 + lm] = f2b(acc[mt][nt][r4] + bv[nt]);
            }
        }
    }
}

// ---------------------------------------------------------------- FUSED transposes (fp32 match + bf16 value)
__global__ __launch_bounds__(256) void transposes_fused_k(
    const float* __restrict__ xm, float* __restrict__ xmT, unsigned short* __restrict__ xmT_bf,
    const unsigned short* __restrict__ ya_bf, unsigned short* __restrict__ yaT)
{
    __shared__ float tlf[32][33];
    __shared__ unsigned short tlb[64][65];
    const int n = blockIdx.y;
    if (blockIdx.x < 576) {
        const int idx = blockIdx.x;
        const int by = idx / 288, bx = idx - by * 288;
        const size_t base = (size_t)n * 64 * LL;
        const int c0 = bx * 32, r0 = by * 32;
        const int tx = threadIdx.x & 31, ty0 = threadIdx.x >> 5;
#pragma unroll
        for (int i = 0; i < 32; i += 8)
            tlf[ty0 + i][tx] = xm[base + (size_t)(r0 + ty0 + i) * LL + c0 + tx];
        __syncthreads();
#pragma unroll
        for (int i = 0; i < 32; i += 8) {
            float v = tlf[tx][ty0 + i];
            size_t o = base + (size_t)(c0 + ty0 + i) * 64 + r0 + tx;
            xmT[o] = v;
            xmT_bf[o] = f2b(v);
        }
    } else {
        const int idx = blockIdx.x - 576;
        const int by = idx / 144, bx = idx - by * 144;
        const size_t base = (size_t)n * LL * CHN;
        const int t0 = bx * 64, e0 = by * 64;
        const int tx = threadIdx.x & 63, ty0 = threadIdx.x >> 6;
#pragma unroll
        for (int i = 0; i < 16; i++) {
            int row = ty0 + i * 4;
            tlb[row][tx] = ya_bf[base + (size_t)(e0 + row) * LL + t0 + tx];
        }
        __syncthreads();
#pragma unroll
        for (int i = 0; i < 16; i++) {
            int row = ty0 + i * 4;
            yaT[base + (size_t)(t0 + row) * CHN + e0 + tx] = tlb[tx][row];
        }
    }
}

// ---------------------------------------------------------------- hashing: codes + squared norms (fp32!)
__global__ __launch_bounds__(256) void hash_k(const float* __restrict__ xmT, const float* __restrict__ rot,
                                              int* __restrict__ codes, float* __restrict__ ssq)
{
    __shared__ float rs[32 * 68];   // [i][f], stride 68, this block's hash only
    const int h = blockIdx.y;
    for (int e = threadIdx.x; e < 2048; e += 256) {
        int hi = e >> 6, f = e & 63;
        rs[hi * 68 + f] = rot[f * 128 + h * 32 + hi];
    }
    __syncthreads();
    int g = blockIdx.x * 256 + threadIdx.x;
    int n = g / LL, t = g % LL;
    float4 x4[16];
    const float* src = xmT + (size_t)g * CC;
#pragma unroll
    for (int f4 = 0; f4 < 16; f4++) x4[f4] = *(const float4*)(src + f4 * 4);
    if (h == 0) {
        float ss = 0.f;
#pragma unroll
        for (int f4 = 0; f4 < 16; f4++)
            ss += x4[f4].x * x4[f4].x + x4[f4].y * x4[f4].y + x4[f4].z * x4[f4].z + x4[f4].w * x4[f4].w;
        ssq[g] = ss;
    }
    float bp = -1e30f, bn = -1e30f;
    int ip = 0, inn = 0;
    for (int i = 0; i < 32; i++) {
        const float* rr = &rs[i * 68];
        float d0 = 0.f, d1 = 0.f, d2 = 0.f, d3 = 0.f;
#pragma unroll
        for (int f4 = 0; f4 < 16; f4++) {
            float4 r4 = *(const float4*)(rr + f4 * 4);
            d0 = fmaf(x4[f4].x, r4.x, d0);
            d1 = fmaf(x4[f4].y, r4.y, d1);
            d2 = fmaf(x4[f4].z, r4.z, d2);
            d3 = fmaf(x4[f4].w, r4.w, d3);
        }
        float d = (d0 + d1) + (d2 + d3);
        if (d > bp) { bp = d; ip = i; }
        if (-d > bn) { bn = -d; inn = i; }
    }
    int code = (bp >= bn) ? ip : (32 + inn);
    codes[(size_t)n * NJ + h * LL + t] = code + h * HBK;
}

// ---------------------------------------------------------------- stable counting sort (256 buckets)
__global__ __launch_bounds__(256) void sort_hist_k(const int* __restrict__ codes, int* __restrict__ hist,
                                                   int* __restrict__ rank)
{
    __shared__ int lhw[4][256];
    const int n = blockIdx.y, seg = blockIdx.x, tid = threadIdx.x;
    const int w = tid >> 6, lane = tid & 63;
    int j = seg * 256 + tid;
    int c = codes[(size_t)n * NJ + j];
    for (int e = tid; e < 1024; e += 256) ((int*)lhw)[e] = 0;
    __syncthreads();
    unsigned long long eq = ~0ull;
#pragma unroll
    for (int b = 0; b < 8; b++) {
        unsigned long long m = __ballot((c >> b) & 1);
        eq &= ((c >> b) & 1) ? m : ~m;
    }
    int rw = __popcll(eq & ((1ull << lane) - 1ull));   // rank within wave (tid order)
    int cntw = __popcll(eq);                           // class count in this wave
    if (rw == 0) lhw[w][c] = cntw;                     // unique (w,c) writer
    __syncthreads();
    int base = 0;
    if (w > 0) base += lhw[0][c];
    if (w > 1) base += lhw[1][c];
    if (w > 2) base += lhw[2][c];
    rank[(size_t)n * NJ + j] = base + rw;
    hist[(size_t)n * NJ + tid * 144 + seg] = lhw[0][tid] + lhw[1][tid] + lhw[2][tid] + lhw[3][tid];
}

__global__ __launch_bounds__(256) void sort_scan_k(int* __restrict__ hist)
{
    const int n = blockIdx.x;
    const int key = threadIdx.x;
    int* hn = hist + (size_t)n * NJ;
    int sum = 0;
    for (int s = 0; s < 144; s++) sum += hn[key * 144 + s];
    __shared__ int sc[256];
    sc[key] = sum;
    __syncthreads();
    for (int off = 1; off < 256; off <<= 1) {
        int v = (key >= off) ? sc[key - off] : 0;
        __syncthreads();
        sc[key] += v;
        __syncthreads();
    }
    int run = sc[key] - sum;   // exclusive prefix
    for (int s = 0; s < 144; s++) { int v = hn[key * 144 + s]; hn[key * 144 + s] = run; run += v; }
}

__global__ __launch_bounds__(256) void sort_scatter_k(const int* __restrict__ codes, const int* __restrict__ rank,
                                                      const int* __restrict__ hist, int* __restrict__ sidx)
{
    const int n = blockIdx.y, seg = blockIdx.x, tid = threadIdx.x;
    int j = seg * 256 + tid;
    int c = codes[(size_t)n * NJ + j];
    int dest = hist[(size_t)n * NJ + c * 144 + seg] + rank[(size_t)n * NJ + j];
    sidx[(size_t)n * NJ + dest] = j;
    // undo[] no longer produced: attn writes O in unsorted (h,t) order directly,
    // and bs is already written unsorted — nothing reads undo anymore.
}

// ---------------------------------------------------------------- MFMA attention v7 = v5 + unsorted O write.
// Epilogue writes O rows at their UNSORTED position (h, t=tIdx[mrow]) instead of
// sorted position k*CHK+mrow. The scatter moves from combfin's read side (L2-miss
// latency on a 75MB buffer, stalls waves) to attn's write side (fire-and-forget).
// Each (k,h,n) block owns a disjoint token set (argsort is a permutation; L%CHK==0
// -> no pad duplicates), so every row is written exactly once. Core loop untouched.
#define QSTR 72     // Q/K row stride in shorts
#define PSTR 164    // P row stride in shorts (conflict-free write quadrants)
__global__ __launch_bounds__(1024, 4) __attribute__((amdgpu_waves_per_eu(4, 4))) void attn_mfma_k(
    const unsigned short* __restrict__ xmT_bf, const unsigned short* __restrict__ yaT,
    const float* __restrict__ ssq, const int* __restrict__ sidx,
    unsigned short* __restrict__ Ouns, float* __restrict__ bs)
{
    __shared__ short Qs[144 * QSTR];
    __shared__ short Ks[144 * QSTR];
    __shared__ short Ps[144 * PSTR];
    __shared__ int   tIdx[432];
    __shared__ int   voff[432];
    __shared__ float nfs[432];
    __shared__ float qlen[432];
    __shared__ float lsum[144];
    __shared__ float linv[144];

    const int k = blockIdx.x, h = blockIdx.y, n = blockIdx.z;
    const int tid = threadIdx.x;
    const int w = tid >> 6, lane = tid & 63;
    const int lm = lane & 15, lq = lane >> 4;
    const size_t sbase = (size_t)n * NJ + (size_t)h * LL;

    if (tid < 432) {
        int cc = tid / CHK, rr = tid - cc * CHK;
        int c = (cc == 0) ? k : (cc == 1 ? (k + NCHUNK - 1) & (NCHUNK - 1) : (k + 1) & (NCHUNK - 1));
        int j = sidx[sbase + c * CHK + rr];
        int t = j % LL;
        tIdx[tid] = t;
        voff[tid] = t * (CHN * 2);
        float m = fmaxf(ssq[(size_t)n * LL + t], 5e-5f);
        float nf = rsqrtf(m);
        nfs[tid] = nf;
        qlen[tid] = m * nf;   // sqrt(m) = |q| clamped
    }
    __syncthreads();   // tIdx/voff/nfs/qlen ready

    // stage Q rows (raw bf16)
    const int sr = tid >> 3, sj = (tid & 7) * 8;
    const int sr2 = (tid + 1024) >> 3, sj2 = (tid & 7) * 8;
    {
        u16x8 v = *(const u16x8*)(xmT_bf + ((size_t)n * LL + tIdx[sr]) * CC + sj);
        *(u16x8*)&Qs[sr * QSTR + sj] = v;
        if (tid < 128) {
            u16x8 v2 = *(const u16x8*)(xmT_bf + ((size_t)n * LL + tIdx[sr2]) * CC + sj2);
            *(u16x8*)&Qs[sr2 * QSTR + sj2] = v2;
        }
    }
    // zero P pad columns 144..159 once (P writes later touch cols 0..143 only)
    for (int e = tid; e < 2304; e += 1024) {
        int r = e >> 4, c = 144 + (e & 15);
        Ps[r * PSTR + c] = 0;
    }
    // T14: issue chunk-1 K loads into registers now (consumed at top of chunk 1)
    u16x8 kreg0, kreg1;
    kreg0 = *(const u16x8*)(xmT_bf + ((size_t)n * LL + tIdx[CHK + sr]) * CC + sj);
    if (tid < 128)
        kreg1 = *(const u16x8*)(xmT_bf + ((size_t)n * LL + tIdx[CHK + sr2]) * CC + sj2);

    const char* vbase = (const char*)(yaT + (size_t)n * LL * CHN + w * 16 + lm);
    f32x4 accO[9];
#pragma unroll
    for (int mt = 0; mt < 9; mt++) accO[mt] = (f32x4){0.f, 0.f, 0.f, 0.f};
    f32x4 accL = (f32x4){0.f, 0.f, 0.f, 0.f};
    bf16x8 onesF, onesL;
#pragma unroll
    for (int i = 0; i < 8; i++) {
        onesF[i] = (short)0x3F80;
        onesL[i] = (lq < 2) ? (short)0x3F80 : (short)0;   // mask pad keys 144..159 (k-step 4, lq>=2)
    }

    for (int cc = 0; cc < 3; cc++) {
        const int c144 = cc * CHK;
        if (cc > 0) {
            *(u16x8*)&Ks[sr * QSTR + sj] = kreg0;
            if (tid < 128) *(u16x8*)&Ks[sr2 * QSTR + sj2] = kreg1;
        }
        if (cc < 2) {
            kreg0 = *(const u16x8*)(xmT_bf + ((size_t)n * LL + tIdx[(cc + 1) * CHK + sr]) * CC + sj);
            if (tid < 128)
                kreg1 = *(const u16x8*)(xmT_bf + ((size_t)n * LL + tIdx[(cc + 1) * CHK + sr2]) * CC + sj2);
        }
        // V B-frag gathers from global — issued early, consumed after QK (latency hidden)
        bf16x8 vfrag[5];
#pragma unroll
        for (int ks = 0; ks < 5; ks++) {
            int kb = ks * 32 + lq * 8;
            if (kb < 144) {
                int4 o0 = *(const int4*)&voff[c144 + kb];
                int4 o1 = *(const int4*)&voff[c144 + kb + 4];
                vfrag[ks][0] = (short)*(const unsigned short*)(vbase + o0.x);
                vfrag[ks][1] = (short)*(const unsigned short*)(vbase + o0.y);
                vfrag[ks][2] = (short)*(const unsigned short*)(vbase + o0.z);
                vfrag[ks][3] = (short)*(const unsigned short*)(vbase + o0.w);
                vfrag[ks][4] = (short)*(const unsigned short*)(vbase + o1.x);
                vfrag[ks][5] = (short)*(const unsigned short*)(vbase + o1.y);
                vfrag[ks][6] = (short)*(const unsigned short*)(vbase + o1.z);
                vfrag[ks][7] = (short)*(const unsigned short*)(vbase + o1.w);
            } else {
                vfrag[ks] = (bf16x8){0, 0, 0, 0, 0, 0, 0, 0};
            }
        }
        __syncthreads();

        // QK (B^T GEMM) + exp; raw scores post-scaled by key norm; P written straight to LDS
        const short* Bsrc = (cc == 0) ? Qs : Ks;
        for (int tt = w; tt < 81; tt += 16) {
            int mt = tt / 9, nt = tt - mt * 9;
            f32x4 c = {0.f, 0.f, 0.f, 0.f};
#pragma unroll
            for (int ks = 0; ks < 2; ks++) {
                bf16x8 a = *(const bf16x8*)&Qs[(mt * 16 + lm) * QSTR + ks * 32 + lq * 8];
                bf16x8 b = *(const bf16x8*)&Bsrc[(nt * 16 + lm) * QSTR + ks * 32 + lq * 8];
                c = __builtin_amdgcn_mfma_f32_16x16x32_bf16(a, b, c, 0, 0, 0);
            }
            float nfk = nfs[c144 + nt * 16 + lm];
#pragma unroll
            for (int r = 0; r < 4; r++) {
                int mrow = mt * 16 + lq * 4 + r;
                float p = __expf(fmaf(c[r], nfk, -qlen[mrow]));
                Ps[mrow * PSTR + nt * 16 + lm] = (short)f2b(p);
            }
        }
        __syncthreads();   // Ps ready (pad cols are permanent zeros)

        // lsum via ones-MFMA (waves 0..8, mt = w)
        if (w < 9) {
#pragma unroll
            for (int ks = 0; ks < 5; ks++) {
                bf16x8 a = *(const bf16x8*)&Ps[(w * 16 + lm) * PSTR + ks * 32 + lq * 8];
                accL = __builtin_amdgcn_mfma_f32_16x16x32_bf16(a, (ks == 4) ? onesL : onesF, accL, 0, 0, 0);
            }
        }
        // PV: 9 m-tiles, V frags in registers
#pragma unroll
        for (int mt = 0; mt < 9; mt++) {
            f32x4 c = accO[mt];
#pragma unroll
            for (int ks = 0; ks < 5; ks++) {
                bf16x8 a = *(const bf16x8*)&Ps[(mt * 16 + lm) * PSTR + ks * 32 + lq * 8];
                c = __builtin_amdgcn_mfma_f32_16x16x32_bf16(a, vfrag[ks], c, 0, 0, 0);
            }
            accO[mt] = c;
        }
    }

    if (w < 9 && lm == 0) {
#pragma unroll
        for (int r = 0; r < 4; r++) lsum[w * 16 + lq * 4 + r] = accL[r];
    }
    __syncthreads();
    if (tid < 144) {
        float l = lsum[tid];
        linv[tid] = 1.0f / l;
        bs[sbase + tIdx[tid]] = qlen[tid] + __logf(l);
    }
    __syncthreads();

    // O written at UNSORTED position (h, tIdx[mrow]) — row-level scatter, 512B/row
#pragma unroll
    for (int mt = 0; mt < 9; mt++) {
        f32x4 c = accO[mt];
#pragma unroll
        for (int r = 0; r < 4; r++) {
            int mrow = mt * 16 + lq * 4 + r;
            Ouns[(sbase + (size_t)tIdx[mrow]) * CHN + w * 16 + lm] = f2b(c[r] * linv[mrow]);
        }
    }
}

// ---------------------------------------------------------------- combine v2 (4 hashes, inline softmax) + transpose + residual
// O is now unsorted (h,t)-ordered: reads are 4 sequential 16KB row-ranges per
// block (was 4 scattered 512B rows per token + an undo indirection).
__global__ __launch_bounds__(256) void combfin_k(
    const unsigned short* __restrict__ Ouns, const float* __restrict__ bs,
    const float* __restrict__ inp, float* __restrict__ out)
{
    __shared__ float ac[32][260];
    __shared__ float pS[4][32];
    const int n = blockIdx.y;
    const int t0 = blockIdx.x * 32;
    const int tid = threadIdx.x;
    if (tid < 128) {
        int hh = tid >> 5, tt = tid & 31;
        pS[hh][tt] = bs[(size_t)n * NJ + (size_t)hh * LL + t0 + tt];
    }
    __syncthreads();
    if (tid < 32) {
        float b0 = pS[0][tid], b1 = pS[1][tid], b2 = pS[2][tid], b3 = pS[3][tid];
        float mx = fmaxf(fmaxf(b0, b1), fmaxf(b2, b3));
        float e0 = __expf(b0 - mx), e1 = __expf(b1 - mx), e2 = __expf(b2 - mx), e3 = __expf(b3 - mx);
        float inv = 1.f / (e0 + e1 + e2 + e3);
        pS[0][tid] = e0 * inv; pS[1][tid] = e1 * inv; pS[2][tid] = e2 * inv; pS[3][tid] = e3 * inv;
    }
    __syncthreads();
    const int g = tid & 63, tq = tid >> 6;
    for (int tt8 = 0; tt8 < 8; tt8++) {
        int t = tq * 8 + tt8;
        float a0 = 0.f, a1 = 0.f, a2 = 0.f, a3 = 0.f;
#pragma unroll
        for (int hh = 0; hh < 4; hh++) {
            size_t row = (size_t)hh * LL + t0 + t;
            float p = pS[hh][t];
            ushort4 u = *(const ushort4*)&Ouns[((size_t)n * NJ + row) * CHN + g * 4];
            a0 = fmaf(p, b2f(u.x), a0);
            a1 = fmaf(p, b2f(u.y), a1);
            a2 = fmaf(p, b2f(u.z), a2);
            a3 = fmaf(p, b2f(u.w), a3);
        }
        *(float4*)&ac[t][g * 4] = make_float4(a0, a1, a2, a3);
    }
    __syncthreads();
    const int tp = tid & 31, er = tid >> 5;
    const float* inN = inp + (size_t)n * LL * CHN;
    float* outN = out + (size_t)n * LL * CHN;
    for (int it = 0; it < 32; it++) {
        int e = er + it * 8;
        size_t o = (size_t)e * LL + t0 + tp;
        outN[o] = ac[tp][e] * 0.1f + inN[o];
    }
}

// ---------------------------------------------------------------- launch
extern "C" void kernel_launch(void* const* d_in, const int* in_sizes, int n_in,
                              void* d_out, int out_size, void* d_ws, size_t ws_size,
                              hipStream_t stream)
{
    (void)in_sizes; (void)n_in; (void)out_size; (void)ws_size;
    const float* input   = (const float*)d_in[0];
    const float* w_match = (const float*)d_in[1];
    const float* b_match = (const float*)d_in[2];
    const float* w_asm   = (const float*)d_in[3];
    const float* b_asm   = (const float*)d_in[4];
    const float* rot     = (const float*)d_in[5];
    float* out = (float*)d_out;

    char* ws = (char*)d_ws;
    size_t off = 0;
    auto alloc = [&](size_t bytes) -> void* {
        void* p = ws + off;
        off += (bytes + 255) & ~(size_t)255;
        return p;
    };
    unsigned short* in_bf  = (unsigned short*)alloc((size_t)NB * LL * CHN * 2);   // = in_hi
    unsigned short* wT_bf  = (unsigned short*)alloc((size_t)9 * CHN * CHN * 2);
    unsigned short* ya_bf  = (unsigned short*)alloc((size_t)NB * LL * CHN * 2);
    unsigned short* yaT    = (unsigned short*)alloc((size_t)NB * LL * CHN * 2);
    float* xm     = (float*)alloc((size_t)NB * LL * CC * 4);
    float* xmT    = (float*)alloc((size_t)NB * LL * CC * 4);
    unsigned short* xmT_bf = (unsigned short*)alloc((size_t)NB * LL * CC * 2);
    float* ssq    = (float*)alloc((size_t)NB * LL * 4);
    int*   codes  = (int*)  alloc((size_t)NB * NJ * 4);
    int*   rank   = (int*)  alloc((size_t)NB * NJ * 4);
    int*   hist   = (int*)  alloc((size_t)NB * NJ * 4);
    int*   sidx   = (int*)  alloc((size_t)NB * NJ * 4);
    float* bs     = (float*)alloc((size_t)NB * NJ * 4);
    unsigned short* Ouns = (unsigned short*)alloc((size_t)NB * NJ * CHN * 2);
    unsigned short* wmT_hi = (unsigned short*)alloc((size_t)9 * 64 * CHN * 2);
    unsigned short* wmT_lo = (unsigned short*)alloc((size_t)9 * 64 * CHN * 2);
    // in_lo (18.9 MB) aliases the head of Ouns (75.5 MB): in_lo is written by
    // cvt_in_hilo_k and last read by convs_fused_k, both strictly before
    // attn_mfma_k writes Ouns on the same stream.
    unsigned short* in_lo = Ouns;

    // input hi/lo split (hi also feeds the value-path conv)
    cvt_in_hilo_k<<<dim3(4608), 256, 0, stream>>>(input, in_bf, in_lo);
    // fused weight prep (match hi/lo + asm transpose)
    cvt_w_fused_k<<<dim3(8, 10, 9), 256, 0, stream>>>(w_match, wmT_hi, wmT_lo, w_asm, wT_bf);
    // fused convs (match split-bf16 + value bf16) — 288 blocks/n
    convs_fused_k<<<dim3(288, NB), 256, 0, stream>>>(in_bf, in_lo, wmT_hi, wmT_lo, b_match, xm,
                                                     wT_bf, b_asm, ya_bf);
    // fused transposes (xm -> xmT/xmT_bf, ya_bf -> yaT) — 1152 blocks/n
    transposes_fused_k<<<dim3(1152, NB), 256, 0, stream>>>(xm, xmT, xmT_bf, ya_bf, yaT);
    // hashing + sort
    hash_k<<<dim3(144, NHASH), 256, 0, stream>>>(xmT, rot, codes, ssq);
    sort_hist_k<<<dim3(144, NB), 256, 0, stream>>>(codes, hist, rank);
    sort_scan_k<<<dim3(NB), 256, 0, stream>>>(hist);
    sort_scatter_k<<<dim3(144, NB), 256, 0, stream>>>(codes, rank, hist, sidx);
    // attention (writes O unsorted) + combine
    attn_mfma_k<<<dim3(NCHUNK, NHASH, NB), 1024, 0, stream>>>(xmT_bf, yaT, ssq, sidx, Ouns, bs);
    combfin_k<<<dim3(288, NB), 256, 0, stream>>>(Ouns, bs, input, out);
}